// Round 9
// baseline (4984.415 us; speedup 1.0000x reference)
//
#include <hip/hip_runtime.h>
#include <hip/hip_cooperative_groups.h>

namespace cg = cooperative_groups;

#define B    1024
#define T    256
#define NBLK 256
#define NTHR 512
#define EPS  1e-5f

typedef _Float16 f16;
typedef _Float16 f16x8 __attribute__((ext_vector_type(8)));
typedef float    f32x4 __attribute__((ext_vector_type(4)));
typedef unsigned long long u64;

// ---- ws byte offsets ----
#define WS_H1X 0u            // f16 [2][1024][256]   h1(t) stored in buf[(t+1)&1]
#define WS_H2X 1048576u      // f16 [2][1024][256]
#define WS_H3X 2097152u      // f16 [2][1024][32]
#define WS_ST  2228224u      // f32 ring [2][8 BGr][1088]  (agent-coherent, cross-XCD)
#define WS_BAR 2297856u      // u32 flag[8 BGr][32 CG] + u32 gflag[8]  (all agent/MALL)

// ---- dynamic LDS byte offsets ----
#define OW1 0        // f16[32][392]  W1 slice, rr = g*8+c, k-contig
#define OW2 25088    // f16[32][520]
#define OW3 58368    // f16[16][296]  (rows 4..15 zero pad)
#define OA1 67840    // f32[256] BN1 scale a
#define OD1 68864    // f32[256] BN1 shift d
#define OB1 69888    // f32[32]
#define OB2 70016    // f32[32]
#define OB3 70144    // f32[4]
#define OA3 70160    // f32[32]
#define OD3 70288    // f32[32]
#define OHW 70416    // f32[72]: Wl(64) Wl2(4) bl(2) bl2(2)
#define OC1 70704    // f32[8][132]
#define OC2 74928    // f32[8][132]
#define OC3 79152    // f32[132]
#define OA2 79680    // f32[256] BN2 scale a
#define OD2 80704    // f32[256] BN2 shift d
#define OG1 81728    // f32[256] gamma1
#define OT1 82752    // f32[256] beta1
#define OG2 83776    // f32[256] gamma2
#define OT2 84800    // f32[256] beta2
#define OG3 85824    // f32[32]  gamma3
#define OT3 85952    // f32[32]  beta3
#define OR1 86080    // f32[8][16] wave-partial stats L1
#define OR2 86592    // f32[8][16] wave-partial stats L2
#define OR3 87104    // f32[8][2]  wave-partial stats L3
#define LDSBYTES 87168

__device__ __forceinline__ float fsigmoid(float v) { return 1.f / (1.f + __expf(-v)); }
__device__ __forceinline__ float ftanh(float v)    { return 1.f - 2.f / (__expf(2.f * v) + 1.f); }

// ---- agent-coherent accessors (MALL) — cross-XCD stats & barrier flags ----
__device__ __forceinline__ float coh_ldf(const float* p) {
    return __hip_atomic_load(p, __ATOMIC_RELAXED, __HIP_MEMORY_SCOPE_AGENT);
}
__device__ __forceinline__ void coh_stf(float* p, float v) {
    __hip_atomic_store(p, v, __ATOMIC_RELAXED, __HIP_MEMORY_SCOPE_AGENT);
}

// ---- intra-XCD (sc0 = L1-bypass, XCD-L2-visible) h-exchange ----
// "BGr = blk&7 groups share an L2" empirically proven by R7's passing h-exchange.
// Loads: one asm block, trailing vmcnt(0) INSIDE, all outputs early-clobber.
__device__ __forceinline__ void ld_h8_sc0(const f16* p, f16x8& d0, f16x8& d1, f16x8& d2,
                                          f16x8& d3, f16x8& d4, f16x8& d5, f16x8& d6, f16x8& d7) {
    asm volatile(
        "global_load_dwordx4 %0, %8, off sc0\n\t"
        "global_load_dwordx4 %1, %8, off offset:64 sc0\n\t"
        "global_load_dwordx4 %2, %8, off offset:128 sc0\n\t"
        "global_load_dwordx4 %3, %8, off offset:192 sc0\n\t"
        "global_load_dwordx4 %4, %8, off offset:256 sc0\n\t"
        "global_load_dwordx4 %5, %8, off offset:320 sc0\n\t"
        "global_load_dwordx4 %6, %8, off offset:384 sc0\n\t"
        "global_load_dwordx4 %7, %8, off offset:448 sc0\n\t"
        "s_waitcnt vmcnt(0)"
        : "=&v"(d0), "=&v"(d1), "=&v"(d2), "=&v"(d3),
          "=&v"(d4), "=&v"(d5), "=&v"(d6), "=&v"(d7)
        : "v"(p) : "memory");
}
__device__ __forceinline__ void ld_h16_sc0(const f16* p1, const f16* p2,
                                           f16x8& a0, f16x8& a1, f16x8& a2, f16x8& a3,
                                           f16x8& a4, f16x8& a5, f16x8& a6, f16x8& a7,
                                           f16x8& b0_, f16x8& b1_, f16x8& b2_, f16x8& b3_,
                                           f16x8& b4_, f16x8& b5_, f16x8& b6_, f16x8& b7_) {
    asm volatile(
        "global_load_dwordx4 %0, %16, off sc0\n\t"
        "global_load_dwordx4 %1, %16, off offset:64 sc0\n\t"
        "global_load_dwordx4 %2, %16, off offset:128 sc0\n\t"
        "global_load_dwordx4 %3, %16, off offset:192 sc0\n\t"
        "global_load_dwordx4 %4, %16, off offset:256 sc0\n\t"
        "global_load_dwordx4 %5, %16, off offset:320 sc0\n\t"
        "global_load_dwordx4 %6, %16, off offset:384 sc0\n\t"
        "global_load_dwordx4 %7, %16, off offset:448 sc0\n\t"
        "global_load_dwordx4 %8, %17, off sc0\n\t"
        "global_load_dwordx4 %9, %17, off offset:64 sc0\n\t"
        "global_load_dwordx4 %10, %17, off offset:128 sc0\n\t"
        "global_load_dwordx4 %11, %17, off offset:192 sc0\n\t"
        "global_load_dwordx4 %12, %17, off offset:256 sc0\n\t"
        "global_load_dwordx4 %13, %17, off offset:320 sc0\n\t"
        "global_load_dwordx4 %14, %17, off offset:384 sc0\n\t"
        "global_load_dwordx4 %15, %17, off offset:448 sc0\n\t"
        "s_waitcnt vmcnt(0)"
        : "=&v"(a0), "=&v"(a1), "=&v"(a2), "=&v"(a3),
          "=&v"(a4), "=&v"(a5), "=&v"(a6), "=&v"(a7),
          "=&v"(b0_), "=&v"(b1_), "=&v"(b2_), "=&v"(b3_),
          "=&v"(b4_), "=&v"(b5_), "=&v"(b6_), "=&v"(b7_)
        : "v"(p1), "v"(p2) : "memory");
}
__device__ __forceinline__ void ld_h9_sc0(const f16* p1, const f16* p2,
                                          f16x8& a0, f16x8& a1, f16x8& a2, f16x8& a3,
                                          f16x8& a4, f16x8& a5, f16x8& a6, f16x8& a7, f16x8& a8) {
    asm volatile(
        "global_load_dwordx4 %0, %9, off sc0\n\t"
        "global_load_dwordx4 %1, %9, off offset:64 sc0\n\t"
        "global_load_dwordx4 %2, %9, off offset:128 sc0\n\t"
        "global_load_dwordx4 %3, %9, off offset:192 sc0\n\t"
        "global_load_dwordx4 %4, %9, off offset:256 sc0\n\t"
        "global_load_dwordx4 %5, %9, off offset:320 sc0\n\t"
        "global_load_dwordx4 %6, %9, off offset:384 sc0\n\t"
        "global_load_dwordx4 %7, %9, off offset:448 sc0\n\t"
        "global_load_dwordx4 %8, %10, off sc0\n\t"
        "s_waitcnt vmcnt(0)"
        : "=&v"(a0), "=&v"(a1), "=&v"(a2), "=&v"(a3), "=&v"(a4),
          "=&v"(a5), "=&v"(a6), "=&v"(a7), "=&v"(a8)
        : "v"(p1), "v"(p2) : "memory");
}
__device__ __forceinline__ void ld_h4_sc0(const f16* p, f16x8& d0, f16x8& d1, f16x8& d2, f16x8& d3) {
    asm volatile(
        "global_load_dwordx4 %0, %4, off sc0\n\t"
        "global_load_dwordx4 %1, %4, off offset:16 sc0\n\t"
        "global_load_dwordx4 %2, %4, off offset:32 sc0\n\t"
        "global_load_dwordx4 %3, %4, off offset:48 sc0\n\t"
        "s_waitcnt vmcnt(0)"
        : "=&v"(d0), "=&v"(d1), "=&v"(d2), "=&v"(d3)
        : "v"(p) : "memory");
}
__device__ __forceinline__ void st_h2_sc0(f16* p, f16 v) {
    asm volatile("global_store_short %0, %1, off sc0" :: "v"(p), "v"(v) : "memory");
}

__global__ void __launch_bounds__(NTHR) cryptonet_kernel(
    const float* __restrict__ x,
    const float* __restrict__ Wih1, const float* __restrict__ Whh1,
    const float* __restrict__ bih1, const float* __restrict__ bhh1,
    const float* __restrict__ g1v,  const float* __restrict__ b1v,
    const float* __restrict__ Wih2, const float* __restrict__ Whh2,
    const float* __restrict__ bih2, const float* __restrict__ bhh2,
    const float* __restrict__ g2v,  const float* __restrict__ b2v,
    const float* __restrict__ Wih3, const float* __restrict__ Whh3,
    const float* __restrict__ bih3, const float* __restrict__ bhh3,
    const float* __restrict__ g3v,  const float* __restrict__ b3v,
    const float* __restrict__ Wl,   const float* __restrict__ bl,
    const float* __restrict__ Wl2,  const float* __restrict__ bl2,
    float* __restrict__ out, float* __restrict__ ws)
{
    cg::grid_group grid = cg::this_grid();
    const int tid  = threadIdx.x;
    const int blk  = blockIdx.x;
    const int CG   = blk >> 3;        // 0..31 channel group (8 ch of H1/H2, 1 ch of H3)
    const int BGr  = blk & 7;         // 0..7 batch group == XCD (R7-validated)
    const int b0   = BGr * 128;
    const int wv   = tid >> 6;        // wave = m-tile 0..7
    const int lane = tid & 63;
    const int q    = lane >> 4;       // quad
    const int mlo  = lane & 15;

    extern __shared__ char smraw[];
    f16*   w1  = (f16*)(smraw + OW1);
    f16*   w2  = (f16*)(smraw + OW2);
    f16*   w3  = (f16*)(smraw + OW3);
    float* sA1 = (float*)(smraw + OA1);
    float* sD1 = (float*)(smraw + OD1);
    float* sA2 = (float*)(smraw + OA2);
    float* sD2 = (float*)(smraw + OD2);
    float* sB1 = (float*)(smraw + OB1);
    float* sB2 = (float*)(smraw + OB2);
    float* sB3 = (float*)(smraw + OB3);
    float* sA3 = (float*)(smraw + OA3);
    float* sD3 = (float*)(smraw + OD3);
    float* sHW = (float*)(smraw + OHW);
    float* c1  = (float*)(smraw + OC1);
    float* c2  = (float*)(smraw + OC2);
    float* c3  = (float*)(smraw + OC3);
    float* sG1 = (float*)(smraw + OG1);
    float* sT1 = (float*)(smraw + OT1);
    float* sG2 = (float*)(smraw + OG2);
    float* sT2 = (float*)(smraw + OT2);
    float* sG3 = (float*)(smraw + OG3);
    float* sT3 = (float*)(smraw + OT3);
    float* sR1 = (float*)(smraw + OR1);   // [8][16] wave partials st1
    float* sR2 = (float*)(smraw + OR2);   // [8][16] wave partials st2
    float* sR3 = (float*)(smraw + OR3);   // [8][2]  wave partials st3

    char* ws8 = (char*)ws;
    f16*   h1x   = (f16*)(ws8 + WS_H1X);
    f16*   h2x   = (f16*)(ws8 + WS_H2X);
    f16*   h3x   = (f16*)(ws8 + WS_H3X);
    float* stats = (float*)(ws8 + WS_ST);     // [2][8][1088] per-BGr sliced, agent-coherent
    unsigned* bar   = (unsigned*)(ws8 + WS_BAR);   // [8][32] arrival flags (agent)
    unsigned* gflag = bar + 256;                   // [8] per-XCD phase-complete (agent)

    // ================= init: weights -> LDS (fp16), biases, zero state =================
    for (int idx = tid; idx < 32 * 384; idx += NTHR) {
        const int rr = idx / 384, k = idx - rr * 384;
        const int j = (rr >> 3) * 256 + CG * 8 + (rr & 7);
        const float v = (k < 128) ? Wih1[(size_t)j * 128 + k] : Whh1[(size_t)j * 256 + (k - 128)];
        w1[rr * 392 + k] = (f16)v;
    }
    for (int idx = tid; idx < 32 * 512; idx += NTHR) {
        const int rr = idx >> 9, k = idx & 511;
        const int j = (rr >> 3) * 256 + CG * 8 + (rr & 7);
        const float v = (k < 256) ? Wih2[(size_t)j * 256 + k] : Whh2[(size_t)j * 256 + (k - 256)];
        w2[rr * 520 + k] = (f16)v;
    }
    for (int idx = tid; idx < 16 * 296; idx += NTHR) w3[idx] = (f16)0.f;
    __syncthreads();
    for (int idx = tid; idx < 4 * 288; idx += NTHR) {
        const int rr = idx / 288, k = idx - rr * 288;  // rr = gate g
        const int j = rr * 32 + CG;
        const float v = (k < 256) ? Wih3[(size_t)j * 256 + k] : Whh3[(size_t)j * 32 + (k - 256)];
        w3[rr * 296 + k] = (f16)v;
    }
    if (tid < 32) {
        const int j = (tid >> 3) * 256 + CG * 8 + (tid & 7);
        sB1[tid] = bih1[j] + bhh1[j];
        sB2[tid] = bih2[j] + bhh2[j];
    }
    if (tid >= 32 && tid < 36) {
        const int g = tid - 32;
        sB3[g] = bih3[g * 32 + CG] + bhh3[g * 32 + CG];
    }
    if (tid >= 64 && tid < 136) {
        const int i = tid - 64;
        float v;
        if (i < 64) v = Wl[i];
        else if (i < 68) v = Wl2[i - 64];
        else if (i < 70) v = bl[i - 68];
        else v = bl2[i - 70];
        sHW[i] = v;
    }
    if (tid < 256) {                   // BN param tables -> LDS
        sG1[tid] = g1v[tid]; sT1[tid] = b1v[tid];
        sG2[tid] = g2v[tid]; sT2[tid] = b2v[tid];
        if (tid < 32) { sG3[tid] = g3v[tid]; sT3[tid] = b3v[tid]; }
    }
    for (int i = tid; i < 8 * 132; i += NTHR) { c1[i] = 0.f; c2[i] = 0.f; }
    if (tid < 132) c3[tid] = 0.f;
    // zero global: H1X[0], H2X[0], H3X[0], barrier flags (ws poisoned each call).
    {
        unsigned int* z1 = (unsigned int*)h1x;
        unsigned int* z2 = (unsigned int*)h2x;
        unsigned int* z3 = (unsigned int*)h3x;
        const int gt = blk * NTHR + tid, gs = NBLK * NTHR;
        for (int i = gt; i < 131072; i += gs) z1[i] = 0u;   // buf 0 (t=-1)
        for (int i = gt; i < 131072; i += gs) z2[i] = 0u;
        for (int i = gt; i < 16384;  i += gs) z3[i] = 0u;
        for (int i = gt; i < 264;    i += gs) bar[i] = 0u;  // 256 flags + 8 gflag
    }
    grid.sync();   // CG barrier once: wbl2+inv publishes zeroed state to all XCDs.
                   // After this: h via sc0 (XCD-L2), stats/flags via sc1 (MALL).

    // pointwise for L1/L2 (8 ch per block): gates land as
    // lane n<8: acc0 = i-gate, acc1 = g-gate; lane n+8: acc0 = f, acc1 = o.
    auto pointwise12 = [&](float* cst, f16* hdst, float* redp, const float* bias,
                           f32x4 acc0, f32x4 acc1) {
        float fr[4], orr[4];
        #pragma unroll
        for (int r = 0; r < 4; ++r) {
            fr[r]  = __shfl_xor(acc0[r], 8);
            orr[r] = __shfl_xor(acc1[r], 8);
        }
        float s = 0.f, sq = 0.f;
        const int c = mlo & 7;
        if (mlo < 8) {
            const float bi = bias[c], bf = bias[8 + c], bg = bias[16 + c], bo = bias[24 + c];
            float4 cc = *(float4*)&cst[c * 132 + wv * 16 + q * 4];
            float cv[4] = {cc.x, cc.y, cc.z, cc.w};
            #pragma unroll
            for (int r = 0; r < 4; ++r) {
                const float gi = fsigmoid(acc0[r] + bi);
                const float gf = fsigmoid(fr[r] + bf);
                const float gg = ftanh(acc1[r] + bg);
                const float go = fsigmoid(orr[r] + bo);
                const float cn = gf * cv[r] + gi * gg;
                cv[r] = cn;
                const f16 h16 = (f16)(go * ftanh(cn));
                st_h2_sc0(&hdst[(size_t)(b0 + wv * 16 + q * 4 + r) * 256 + CG * 8 + c], h16);
                const float hq = (float)h16;
                s += hq; sq += hq * hq;
            }
            *(float4*)&cst[c * 132 + wv * 16 + q * 4] = make_float4(cv[0], cv[1], cv[2], cv[3]);
        }
        s  += __shfl_xor(s, 16);  s  += __shfl_xor(s, 32);
        sq += __shfl_xor(sq, 16); sq += __shfl_xor(sq, 32);
        if (mlo < 8 && q == 0) {
            redp[wv * 16 + c * 2]     = s;
            redp[wv * 16 + c * 2 + 1] = sq;
        }
    };

    // x-prefetch registers for L1 (loaded during previous barrier wait; x is immutable, cached)
    f16x8 xpre[4];
    auto loadx = [&](int t) {
        if (t < T) {
            const int brow = b0 + wv * 16 + mlo;
            #pragma unroll
            for (int kt = 0; kt < 4; ++kt) {
                const float* xp = x + ((size_t)brow * T + t) * 128 + kt * 32 + q * 8;
                const float4 u = *(const float4*)xp;
                const float4 v = *(const float4*)(xp + 4);
                f16x8 a;
                a[0] = (f16)u.x; a[1] = (f16)u.y; a[2] = (f16)u.z; a[3] = (f16)u.w;
                a[4] = (f16)v.x; a[5] = (f16)v.y; a[6] = (f16)v.z; a[7] = (f16)v.w;
                xpre[kt] = a;
            }
        }
    };
    loadx(0);

    // ================= pipelined time loop =================
    // phase s computes: L1(s), L2(s-1), L3(s-2), head(s-3).
    // Sync: flat arrival stores -> 8 CG0 aggregators poll 2 lines -> everyone polls 1 line.
    for (int s = 0; s < T + 3; ++s) {
        const int t2 = s - 1, t3 = s - 2, th = s - 3;

        // ---------- BN folds (sum 8 per-BGr stat partials via coherent loads) ----------
        if (t2 >= 0 && t2 < T && tid < 256) {            // BN1(t2) for L2
            const float* sp = stats + (size_t)(t2 & 1) * 8704;
            float sv = 0.f, qv = 0.f;
            #pragma unroll
            for (int g = 0; g < 8; ++g) {
                sv += coh_ldf(sp + g * 1088 + tid * 2);
                qv += coh_ldf(sp + g * 1088 + tid * 2 + 1);
            }
            const float mu = sv * (1.f / B);
            const float var = qv * (1.f / B) - mu * mu;
            const float a = sG1[tid] * rsqrtf(var + EPS);
            sA1[tid] = a; sD1[tid] = sT1[tid] - mu * a;
        }
        if (t3 >= 0 && t3 < T && tid >= 256) {           // BN2(t3) for L3
            const int ch = tid - 256;
            const float* sp = stats + (size_t)(t3 & 1) * 8704 + 512;
            float sv = 0.f, qv = 0.f;
            #pragma unroll
            for (int g = 0; g < 8; ++g) {
                sv += coh_ldf(sp + g * 1088 + ch * 2);
                qv += coh_ldf(sp + g * 1088 + ch * 2 + 1);
            }
            const float mu = sv * (1.f / B);
            const float var = qv * (1.f / B) - mu * mu;
            const float a = sG2[ch] * rsqrtf(var + EPS);
            sA2[ch] = a; sD2[ch] = sT2[ch] - mu * a;
        }
        if (CG == 0 && th >= 0 && tid < 32) {            // BN3(th) for head
            const float* sp = stats + (size_t)(th & 1) * 8704 + 1024;
            float sv = 0.f, qv = 0.f;
            #pragma unroll
            for (int g = 0; g < 8; ++g) {
                sv += coh_ldf(sp + g * 1088 + tid * 2);
                qv += coh_ldf(sp + g * 1088 + tid * 2 + 1);
            }
            const float mu = sv * (1.f / B);
            const float var = qv * (1.f / B) - mu * mu;
            const float a = sG3[tid] * rsqrtf(var + EPS);
            sA3[tid] = a; sD3[tid] = sT3[tid] - mu * a;
        }
        __syncthreads();

        // ---------- L1(s) ----------
        if (s < T) {
            const f16* h1p = h1x + (size_t)(s & 1) * B * 256;         // h1(s-1)
            f16*       h1c = h1x + (size_t)((s & 1) ^ 1) * B * 256;   // h1(s)
            const int brow = b0 + wv * 16 + mlo;
            f16x8 af[12];
            #pragma unroll
            for (int kt = 0; kt < 4; ++kt) af[kt] = xpre[kt];         // prefetched x
            ld_h8_sc0(h1p + (size_t)brow * 256 + q * 8,
                      af[4], af[5], af[6], af[7], af[8], af[9], af[10], af[11]);
            f32x4 acc0 = {0.f, 0.f, 0.f, 0.f}, acc1 = {0.f, 0.f, 0.f, 0.f};
            #pragma unroll
            for (int kt = 0; kt < 12; ++kt) {
                const f16x8 bf0 = *(const f16x8*)(w1 + mlo * 392 + kt * 32 + q * 8);
                const f16x8 bf1 = *(const f16x8*)(w1 + (16 + mlo) * 392 + kt * 32 + q * 8);
                acc0 = __builtin_amdgcn_mfma_f32_16x16x32_f16(af[kt], bf0, acc0, 0, 0, 0);
                acc1 = __builtin_amdgcn_mfma_f32_16x16x32_f16(af[kt], bf1, acc1, 0, 0, 0);
            }
            pointwise12(c1, h1c, sR1, sB1, acc0, acc1);
        }

        // ---------- L2(t2) : BN1 folded into A-frags ----------
        if (t2 >= 0 && t2 < T) {
            const f16* h1n = h1x + (size_t)(s & 1) * B * 256;          // h1(t2)
            const f16* h2p = h2x + (size_t)((s & 1) ^ 1) * B * 256;    // h2(t2-1)
            f16*       h2c = h2x + (size_t)(s & 1) * B * 256;          // h2(t2)
            const int brow = b0 + wv * 16 + mlo;
            f16x8 af[16];
            ld_h16_sc0(h1n + (size_t)brow * 256 + q * 8,
                       h2p + (size_t)brow * 256 + q * 8,
                       af[0], af[1], af[2], af[3], af[4], af[5], af[6], af[7],
                       af[8], af[9], af[10], af[11], af[12], af[13], af[14], af[15]);
            #pragma unroll
            for (int kt = 0; kt < 8; ++kt) {   // fold z1 = a*h1 + d
                const int k = kt * 32 + q * 8;
                const float4 aa0 = *(const float4*)&sA1[k];
                const float4 aa1 = *(const float4*)&sA1[k + 4];
                const float4 dd0 = *(const float4*)&sD1[k];
                const float4 dd1 = *(const float4*)&sD1[k + 4];
                f16x8 a = af[kt];
                a[0] = (f16)(aa0.x * (float)a[0] + dd0.x);
                a[1] = (f16)(aa0.y * (float)a[1] + dd0.y);
                a[2] = (f16)(aa0.z * (float)a[2] + dd0.z);
                a[3] = (f16)(aa0.w * (float)a[3] + dd0.w);
                a[4] = (f16)(aa1.x * (float)a[4] + dd1.x);
                a[5] = (f16)(aa1.y * (float)a[5] + dd1.y);
                a[6] = (f16)(aa1.z * (float)a[6] + dd1.z);
                a[7] = (f16)(aa1.w * (float)a[7] + dd1.w);
                af[kt] = a;
            }
            f32x4 acc0 = {0.f, 0.f, 0.f, 0.f}, acc1 = {0.f, 0.f, 0.f, 0.f};
            #pragma unroll
            for (int kt = 0; kt < 16; ++kt) {
                const f16x8 bf0 = *(const f16x8*)(w2 + mlo * 520 + kt * 32 + q * 8);
                const f16x8 bf1 = *(const f16x8*)(w2 + (16 + mlo) * 520 + kt * 32 + q * 8);
                acc0 = __builtin_amdgcn_mfma_f32_16x16x32_f16(af[kt], bf0, acc0, 0, 0, 0);
                acc1 = __builtin_amdgcn_mfma_f32_16x16x32_f16(af[kt], bf1, acc1, 0, 0, 0);
            }
            pointwise12(c2, h2c, sR2, sB2, acc0, acc1);
        }

        // ---------- L3(t3) : BN2 folded ----------
        if (t3 >= 0 && t3 < T) {
            const f16* h2n = h2x + (size_t)((s & 1) ^ 1) * B * 256;    // h2(t3)
            const f16* h3p = h3x + (size_t)(s & 1) * B * 32;           // h3(t3-1)
            f16*       h3c = h3x + (size_t)((s & 1) ^ 1) * B * 32;     // h3(t3)
            const int brow = b0 + wv * 16 + mlo;
            f16x8 af[9];
            ld_h9_sc0(h2n + (size_t)brow * 256 + q * 8,
                      h3p + (size_t)brow * 32 + q * 8,
                      af[0], af[1], af[2], af[3], af[4], af[5], af[6], af[7], af[8]);
            #pragma unroll
            for (int kt = 0; kt < 8; ++kt) {   // fold z2
                const int k = kt * 32 + q * 8;
                const float4 aa0 = *(const float4*)&sA2[k];
                const float4 aa1 = *(const float4*)&sA2[k + 4];
                const float4 dd0 = *(const float4*)&sD2[k];
                const float4 dd1 = *(const float4*)&sD2[k + 4];
                f16x8 a = af[kt];
                a[0] = (f16)(aa0.x * (float)a[0] + dd0.x);
                a[1] = (f16)(aa0.y * (float)a[1] + dd0.y);
                a[2] = (f16)(aa0.z * (float)a[2] + dd0.z);
                a[3] = (f16)(aa0.w * (float)a[3] + dd0.w);
                a[4] = (f16)(aa1.x * (float)a[4] + dd1.x);
                a[5] = (f16)(aa1.y * (float)a[5] + dd1.y);
                a[6] = (f16)(aa1.z * (float)a[6] + dd1.z);
                a[7] = (f16)(aa1.w * (float)a[7] + dd1.w);
                af[kt] = a;
            }
            f32x4 acc0 = {0.f, 0.f, 0.f, 0.f};
            #pragma unroll
            for (int kt = 0; kt < 9; ++kt) {
                const f16x8 bf0 = *(const f16x8*)(w3 + mlo * 296 + kt * 32 + q * 8);
                acc0 = __builtin_amdgcn_mfma_f32_16x16x32_f16(af[kt], bf0, acc0, 0, 0, 0);
            }
            float gi[4], gf_[4], gg_[4], go_[4];
            #pragma unroll
            for (int r = 0; r < 4; ++r) {
                gi[r]  = __shfl(acc0[r], (lane & 48) + 0);
                gf_[r] = __shfl(acc0[r], (lane & 48) + 1);
                gg_[r] = __shfl(acc0[r], (lane & 48) + 2);
                go_[r] = __shfl(acc0[r], (lane & 48) + 3);
            }
            float s_ = 0.f, sq = 0.f;
            if (mlo == 0) {
                float4 cc = *(float4*)&c3[wv * 16 + q * 4];
                float cv[4] = {cc.x, cc.y, cc.z, cc.w};
                #pragma unroll
                for (int r = 0; r < 4; ++r) {
                    const float i_ = fsigmoid(gi[r] + sB3[0]);
                    const float f_ = fsigmoid(gf_[r] + sB3[1]);
                    const float g_ = ftanh(gg_[r] + sB3[2]);
                    const float o_ = fsigmoid(go_[r] + sB3[3]);
                    const float cn = f_ * cv[r] + i_ * g_;
                    cv[r] = cn;
                    const f16 h16 = (f16)(o_ * ftanh(cn));
                    st_h2_sc0(&h3c[(size_t)(b0 + wv * 16 + q * 4 + r) * 32 + CG], h16);
                    const float hq = (float)h16;
                    s_ += hq; sq += hq * hq;
                }
                *(float4*)&c3[wv * 16 + q * 4] = make_float4(cv[0], cv[1], cv[2], cv[3]);
            }
            s_ += __shfl_xor(s_, 16); s_ += __shfl_xor(s_, 32);
            sq += __shfl_xor(sq, 16); sq += __shfl_xor(sq, 32);
            if (lane == 0) { sR3[wv * 2] = s_; sR3[wv * 2 + 1] = sq; }
        }

        // ---------- head(th) ----------
        if (CG == 0 && th >= 0) {
            const f16* hp3 = h3x + (size_t)(s & 1) * B * 32;   // h3(th)
            if (lane < 16) {
                const int b = b0 + wv * 16 + lane;
                const f16* hp = hp3 + (size_t)b * 32;
                f16x8 hv0, hv1, hv2, hv3;
                ld_h4_sc0(hp, hv0, hv1, hv2, hv3);
                float zz[32];
                #pragma unroll
                for (int k2 = 0; k2 < 8; ++k2) {
                    zz[k2]      = (float)hv0[k2];
                    zz[8 + k2]  = (float)hv1[k2];
                    zz[16 + k2] = (float)hv2[k2];
                    zz[24 + k2] = (float)hv3[k2];
                }
                float y0 = sHW[68], y1 = sHW[69];
                #pragma unroll
                for (int ch = 0; ch < 32; ++ch) {
                    const float z = sA3[ch] * zz[ch] + sD3[ch];
                    y0 += sHW[ch] * z; y1 += sHW[32 + ch] * z;
                }
                y0 = fmaxf(y0, 0.f); y1 = fmaxf(y1, 0.f);
                const float u0 = sHW[64] * y0 + sHW[65] * y1 + sHW[70];
                const float u1 = sHW[66] * y0 + sHW[67] * y1 + sHW[71];
                const float m = fmaxf(u0, u1);
                const float e0 = __expf(u0 - m), e1 = __expf(u1 - m);
                const float inv = 1.f / (e0 + e1);
                *(float2*)&out[((size_t)b * T + th) * 2] = make_float2(e0 * inv, e1 * inv);
            }
        }

        // ---------- stat reduce + hierarchical MALL barrier ----------
        if (s < T + 2) {
            __syncthreads();   // all waves' h stores (L2) + LDS partials drained
            // cross-wave reduction -> per-BGr sliced agent stores (no atomics, private lines)
            if (s < T && tid < 16) {
                float v = sR1[tid];
                #pragma unroll
                for (int w = 1; w < 8; ++w) v += sR1[w * 16 + tid];
                coh_stf(stats + (size_t)(s & 1) * 8704 + BGr * 1088 + CG * 16 + tid, v);
            }
            if (t2 >= 0 && t2 < T && tid >= 16 && tid < 32) {
                const int i = tid - 16;
                float v = sR2[i];
                #pragma unroll
                for (int w = 1; w < 8; ++w) v += sR2[w * 16 + i];
                coh_stf(stats + (size_t)(t2 & 1) * 8704 + BGr * 1088 + 512 + CG * 16 + i, v);
            }
            if (t3 >= 0 && t3 < T && tid >= 32 && tid < 34) {
                const int i = tid - 32;
                float v = sR3[i];
                #pragma unroll
                for (int w = 1; w < 8; ++w) v += sR3[w * 2 + i];
                coh_stf(stats + (size_t)(t3 & 1) * 8704 + BGr * 1088 + 1024 + CG * 2 + i, v);
            }
            __syncthreads();   // reducer sc1 stores drained (vmcnt(0) per wave before s_barrier)
            const unsigned tgt = (unsigned)(s + 1);
            if (tid == 0)      // flat arrival store (proven primitive)
                __hip_atomic_store(bar + BGr * 32 + CG, tgt,
                                   __ATOMIC_RELAXED, __HIP_MEMORY_SCOPE_AGENT);
            loadx(s + 1);      // hide next x load+cvt under barrier wait
            if (wv == 0) {
                if (CG == 0) {
                    // aggregator: poll own group's 32 flags (2 MALL lines)
                    const unsigned* fp = bar + BGr * 32 + (lane & 31);
                    for (;;) {
                        const unsigned v = __hip_atomic_load(fp, __ATOMIC_RELAXED,
                                                             __HIP_MEMORY_SCOPE_AGENT);
                        if (__all(v >= tgt)) break;
                        __builtin_amdgcn_s_sleep(1);
                    }
                    if (lane == 0)
                        __hip_atomic_store(gflag + BGr, tgt,
                                           __ATOMIC_RELAXED, __HIP_MEMORY_SCOPE_AGENT);
                }
                // everyone: poll 8 gflags (1 MALL line)
                const unsigned* gp = gflag + (lane & 7);
                for (;;) {
                    const unsigned v = __hip_atomic_load(gp, __ATOMIC_RELAXED,
                                                         __HIP_MEMORY_SCOPE_AGENT);
                    if (__all(v >= tgt)) break;
                    __builtin_amdgcn_s_sleep(1);
                }
            }
            __syncthreads();
        }
    }
}

extern "C" void kernel_launch(void* const* d_in, const int* in_sizes, int n_in,
                              void* d_out, int out_size, void* d_ws, size_t ws_size,
                              hipStream_t stream) {
    const float* x    = (const float*)d_in[0];
    const float* Wih1 = (const float*)d_in[1];
    const float* Whh1 = (const float*)d_in[2];
    const float* bih1 = (const float*)d_in[3];
    const float* bhh1 = (const float*)d_in[4];
    const float* g1   = (const float*)d_in[5];
    const float* b1   = (const float*)d_in[6];
    const float* Wih2 = (const float*)d_in[7];
    const float* Whh2 = (const float*)d_in[8];
    const float* bih2 = (const float*)d_in[9];
    const float* bhh2 = (const float*)d_in[10];
    const float* g2   = (const float*)d_in[11];
    const float* b2   = (const float*)d_in[12];
    const float* Wih3 = (const float*)d_in[13];
    const float* Whh3 = (const float*)d_in[14];
    const float* bih3 = (const float*)d_in[15];
    const float* bhh3 = (const float*)d_in[16];
    const float* g3   = (const float*)d_in[17];
    const float* b3   = (const float*)d_in[18];
    const float* Wl   = (const float*)d_in[19];
    const float* bl   = (const float*)d_in[20];
    const float* Wl2  = (const float*)d_in[21];
    const float* bl2  = (const float*)d_in[22];
    float* out = (float*)d_out;
    float* ws  = (float*)d_ws;

    const int dyn_lds = LDSBYTES;
    hipFuncSetAttribute((const void*)cryptonet_kernel,
                        hipFuncAttributeMaxDynamicSharedMemorySize, dyn_lds);

    void* args[] = { &x, &Wih1, &Whh1, &bih1, &bhh1, &g1, &b1,
                     &Wih2, &Whh2, &bih2, &bhh2, &g2, &b2,
                     &Wih3, &Whh3, &bih3, &bhh3, &g3, &b3,
                     &Wl, &bl, &Wl2, &bl2, &out, &ws };
    hipLaunchCooperativeKernel((const void*)cryptonet_kernel, dim3(NBLK), dim3(NTHR),
                               args, dyn_lds, stream);
}

// Round 10
// 4880.215 us; speedup vs baseline: 1.0214x; 1.0214x over previous
//
#include <hip/hip_runtime.h>
#include <hip/hip_cooperative_groups.h>

namespace cg = cooperative_groups;

#define B    1024
#define T    256
#define NBLK 256
#define NTHR 512
#define EPS  1e-5f

typedef _Float16 f16;
typedef _Float16 f16x8 __attribute__((ext_vector_type(8)));
typedef float    f32x4 __attribute__((ext_vector_type(4)));
typedef unsigned long long u64;

// ---- ws byte offsets ----
#define WS_H1X 0u            // f16 [2][1024][256]   h1(t) stored in buf[(t+1)&1]
#define WS_H2X 1048576u      // f16 [2][1024][256]
#define WS_H3X 2097152u      // f16 [2][1024][32]
#define WS_ST  2228224u      // f32 [2 slot][8704]: st1 [256ch][8g][2] | +4096 st2 | +8192 st3 [32ch][8g][2]
#define WS_BAR 2297856u      // uint flags[256], monotonic epoch values

// ---- dynamic LDS byte offsets ----
#define OW1 0        // f16[32][392]  W1 slice, rr = g*8+c, k-contig
#define OW2 25088    // f16[32][520]
#define OW3 58368    // f16[16][296]  (rows 4..15 zero pad)
#define OA1 67840    // f32[256] BN1 scale a
#define OD1 68864    // f32[256] BN1 shift d
#define OB1 69888    // f32[32]
#define OB2 70016    // f32[32]
#define OB3 70144    // f32[4]
#define OA3 70160    // f32[32]
#define OD3 70288    // f32[32]
#define OHW 70416    // f32[72]: Wl(64) Wl2(4) bl(2) bl2(2)
#define OC1 70704    // f32[8][132]
#define OC2 74928    // f32[8][132]
#define OC3 79152    // f32[132]
#define OA2 79680    // f32[256] BN2 scale a
#define OD2 80704    // f32[256] BN2 shift d
#define OG1 81728    // f32[256] gamma1
#define OT1 82752    // f32[256] beta1
#define OG2 83776    // f32[256] gamma2
#define OT2 84800    // f32[256] beta2
#define OG3 85824    // f32[32]  gamma3
#define OT3 85952    // f32[32]  beta3
#define OR1 86080    // f32[8][16] wave-partial stats L1
#define OR2 86592    // f32[8][16] wave-partial stats L2
#define OR3 87104    // f32[8][2]  wave-partial stats L3
#define LDSBYTES 87168

__device__ __forceinline__ float fsigmoid(float v) { return 1.f / (1.f + __expf(-v)); }
__device__ __forceinline__ float ftanh(float v)    { return 1.f - 2.f / (__expf(2.f * v) + 1.f); }

// ---- agent-coherent accessors (MALL) — cross-XCD stats & barrier flags ----
__device__ __forceinline__ float coh_ldf(const float* p) {
    return __hip_atomic_load(p, __ATOMIC_RELAXED, __HIP_MEMORY_SCOPE_AGENT);
}
__device__ __forceinline__ void coh_stf(float* p, float v) {
    __hip_atomic_store(p, v, __ATOMIC_RELAXED, __HIP_MEMORY_SCOPE_AGENT);
}

// ---- phase mega-load: ALL cross-block reads of the phase in ONE issue window ----
// 4x dwordx4 BN stats (sc0 sc1 = MALL-coherent) + 8x h1 + 8x h2 + 1x h3 (sc0 = XCD-L2).
// Single trailing vmcnt(0) inside the block: all loads in flight concurrently, total
// exposure = max(MALL RTT, L2 RTT). Outputs early-clobber (R6 lesson). Consumers
// data-depend on outputs (no hoist hazard).
__device__ __forceinline__ void ld_phase(const float* sp, const f16* p1, const f16* p2,
                                         const f16* p3,
    f32x4& r0, f32x4& r1, f32x4& r2, f32x4& r3,
    f16x8& d0, f16x8& d1, f16x8& d2, f16x8& d3,
    f16x8& d4, f16x8& d5, f16x8& d6, f16x8& d7,
    f16x8& e0, f16x8& e1, f16x8& e2, f16x8& e3,
    f16x8& e4, f16x8& e5, f16x8& e6, f16x8& e7,
    f16x8& f0) {
    asm volatile(
        "global_load_dwordx4 %0, %21, off sc0 sc1\n\t"
        "global_load_dwordx4 %1, %21, off offset:16 sc0 sc1\n\t"
        "global_load_dwordx4 %2, %21, off offset:32 sc0 sc1\n\t"
        "global_load_dwordx4 %3, %21, off offset:48 sc0 sc1\n\t"
        "global_load_dwordx4 %4, %22, off sc0\n\t"
        "global_load_dwordx4 %5, %22, off offset:64 sc0\n\t"
        "global_load_dwordx4 %6, %22, off offset:128 sc0\n\t"
        "global_load_dwordx4 %7, %22, off offset:192 sc0\n\t"
        "global_load_dwordx4 %8, %22, off offset:256 sc0\n\t"
        "global_load_dwordx4 %9, %22, off offset:320 sc0\n\t"
        "global_load_dwordx4 %10, %22, off offset:384 sc0\n\t"
        "global_load_dwordx4 %11, %22, off offset:448 sc0\n\t"
        "global_load_dwordx4 %12, %23, off sc0\n\t"
        "global_load_dwordx4 %13, %23, off offset:64 sc0\n\t"
        "global_load_dwordx4 %14, %23, off offset:128 sc0\n\t"
        "global_load_dwordx4 %15, %23, off offset:192 sc0\n\t"
        "global_load_dwordx4 %16, %23, off offset:256 sc0\n\t"
        "global_load_dwordx4 %17, %23, off offset:320 sc0\n\t"
        "global_load_dwordx4 %18, %23, off offset:384 sc0\n\t"
        "global_load_dwordx4 %19, %23, off offset:448 sc0\n\t"
        "global_load_dwordx4 %20, %24, off sc0\n\t"
        "s_waitcnt vmcnt(0)"
        : "=&v"(r0), "=&v"(r1), "=&v"(r2), "=&v"(r3),
          "=&v"(d0), "=&v"(d1), "=&v"(d2), "=&v"(d3),
          "=&v"(d4), "=&v"(d5), "=&v"(d6), "=&v"(d7),
          "=&v"(e0), "=&v"(e1), "=&v"(e2), "=&v"(e3),
          "=&v"(e4), "=&v"(e5), "=&v"(e6), "=&v"(e7),
          "=&v"(f0)
        : "v"(sp), "v"(p1), "v"(p2), "v"(p3) : "memory");
}
__device__ __forceinline__ void ld_h4_sc0(const f16* p, f16x8& d0, f16x8& d1, f16x8& d2, f16x8& d3) {
    asm volatile(
        "global_load_dwordx4 %0, %4, off sc0\n\t"
        "global_load_dwordx4 %1, %4, off offset:16 sc0\n\t"
        "global_load_dwordx4 %2, %4, off offset:32 sc0\n\t"
        "global_load_dwordx4 %3, %4, off offset:48 sc0\n\t"
        "s_waitcnt vmcnt(0)"
        : "=&v"(d0), "=&v"(d1), "=&v"(d2), "=&v"(d3)
        : "v"(p) : "memory");
}
__device__ __forceinline__ void st_h2_sc0(f16* p, f16 v) {
    asm volatile("global_store_short %0, %1, off sc0" :: "v"(p), "v"(v) : "memory");
}

__global__ void __launch_bounds__(NTHR) cryptonet_kernel(
    const float* __restrict__ x,
    const float* __restrict__ Wih1, const float* __restrict__ Whh1,
    const float* __restrict__ bih1, const float* __restrict__ bhh1,
    const float* __restrict__ g1v,  const float* __restrict__ b1v,
    const float* __restrict__ Wih2, const float* __restrict__ Whh2,
    const float* __restrict__ bih2, const float* __restrict__ bhh2,
    const float* __restrict__ g2v,  const float* __restrict__ b2v,
    const float* __restrict__ Wih3, const float* __restrict__ Whh3,
    const float* __restrict__ bih3, const float* __restrict__ bhh3,
    const float* __restrict__ g3v,  const float* __restrict__ b3v,
    const float* __restrict__ Wl,   const float* __restrict__ bl,
    const float* __restrict__ Wl2,  const float* __restrict__ bl2,
    float* __restrict__ out, float* __restrict__ ws)
{
    cg::grid_group grid = cg::this_grid();
    const int tid  = threadIdx.x;
    const int blk  = blockIdx.x;
    const int CG   = blk >> 3;        // 0..31 channel group (8 ch of H1/H2, 1 ch of H3)
    const int BGr  = blk & 7;         // 0..7 batch group == XCD (R7-validated)
    const int b0   = BGr * 128;
    const int wv   = tid >> 6;        // wave = m-tile 0..7
    const int lane = tid & 63;
    const int q    = lane >> 4;       // quad
    const int mlo  = lane & 15;

    extern __shared__ char smraw[];
    f16*   w1  = (f16*)(smraw + OW1);
    f16*   w2  = (f16*)(smraw + OW2);
    f16*   w3  = (f16*)(smraw + OW3);
    float* sA1 = (float*)(smraw + OA1);
    float* sD1 = (float*)(smraw + OD1);
    float* sA2 = (float*)(smraw + OA2);
    float* sD2 = (float*)(smraw + OD2);
    float* sB1 = (float*)(smraw + OB1);
    float* sB2 = (float*)(smraw + OB2);
    float* sB3 = (float*)(smraw + OB3);
    float* sA3 = (float*)(smraw + OA3);
    float* sD3 = (float*)(smraw + OD3);
    float* sHW = (float*)(smraw + OHW);
    float* c1  = (float*)(smraw + OC1);
    float* c2  = (float*)(smraw + OC2);
    float* c3  = (float*)(smraw + OC3);
    float* sG1 = (float*)(smraw + OG1);
    float* sT1 = (float*)(smraw + OT1);
    float* sG2 = (float*)(smraw + OG2);
    float* sT2 = (float*)(smraw + OT2);
    float* sG3 = (float*)(smraw + OG3);
    float* sT3 = (float*)(smraw + OT3);
    float* sR1 = (float*)(smraw + OR1);   // [8][16] wave partials st1
    float* sR2 = (float*)(smraw + OR2);   // [8][16] wave partials st2
    float* sR3 = (float*)(smraw + OR3);   // [8][2]  wave partials st3

    char* ws8 = (char*)ws;
    f16*   h1x   = (f16*)(ws8 + WS_H1X);
    f16*   h2x   = (f16*)(ws8 + WS_H2X);
    f16*   h3x   = (f16*)(ws8 + WS_H3X);
    float* stats = (float*)(ws8 + WS_ST);   // [2][8704] channel-major [ch][BGr][2]
    unsigned* bar = (unsigned*)(ws8 + WS_BAR);

    // ================= init: weights -> LDS (fp16), biases, zero state =================
    for (int idx = tid; idx < 32 * 384; idx += NTHR) {
        const int rr = idx / 384, k = idx - rr * 384;
        const int j = (rr >> 3) * 256 + CG * 8 + (rr & 7);
        const float v = (k < 128) ? Wih1[(size_t)j * 128 + k] : Whh1[(size_t)j * 256 + (k - 128)];
        w1[rr * 392 + k] = (f16)v;
    }
    for (int idx = tid; idx < 32 * 512; idx += NTHR) {
        const int rr = idx >> 9, k = idx & 511;
        const int j = (rr >> 3) * 256 + CG * 8 + (rr & 7);
        const float v = (k < 256) ? Wih2[(size_t)j * 256 + k] : Whh2[(size_t)j * 256 + (k - 256)];
        w2[rr * 520 + k] = (f16)v;
    }
    for (int idx = tid; idx < 16 * 296; idx += NTHR) w3[idx] = (f16)0.f;
    __syncthreads();
    for (int idx = tid; idx < 4 * 288; idx += NTHR) {
        const int rr = idx / 288, k = idx - rr * 288;  // rr = gate g
        const int j = rr * 32 + CG;
        const float v = (k < 256) ? Wih3[(size_t)j * 256 + k] : Whh3[(size_t)j * 32 + (k - 256)];
        w3[rr * 296 + k] = (f16)v;
    }
    if (tid < 32) {
        const int j = (tid >> 3) * 256 + CG * 8 + (tid & 7);
        sB1[tid] = bih1[j] + bhh1[j];
        sB2[tid] = bih2[j] + bhh2[j];
    }
    if (tid >= 32 && tid < 36) {
        const int g = tid - 32;
        sB3[g] = bih3[g * 32 + CG] + bhh3[g * 32 + CG];
    }
    if (tid >= 64 && tid < 136) {
        const int i = tid - 64;
        float v;
        if (i < 64) v = Wl[i];
        else if (i < 68) v = Wl2[i - 64];
        else if (i < 70) v = bl[i - 68];
        else v = bl2[i - 70];
        sHW[i] = v;
    }
    if (tid < 256) {                   // BN param tables -> LDS
        sG1[tid] = g1v[tid]; sT1[tid] = b1v[tid];
        sG2[tid] = g2v[tid]; sT2[tid] = b2v[tid];
        if (tid < 32) { sG3[tid] = g3v[tid]; sT3[tid] = b3v[tid]; }
    }
    for (int i = tid; i < 8 * 132; i += NTHR) { c1[i] = 0.f; c2[i] = 0.f; }
    if (tid < 132) c3[tid] = 0.f;
    // zero global: H1X[0], H2X[0], H3X[0], barrier flags (ws poisoned each call).
    // stats need NO zeroing (plain overwrite; all reads guarded to written slots).
    {
        unsigned int* z1 = (unsigned int*)h1x;
        unsigned int* z2 = (unsigned int*)h2x;
        unsigned int* z3 = (unsigned int*)h3x;
        const int gt = blk * NTHR + tid, gs = NBLK * NTHR;
        for (int i = gt; i < 131072; i += gs) z1[i] = 0u;   // buf 0 (t=-1)
        for (int i = gt; i < 131072; i += gs) z2[i] = 0u;
        for (int i = gt; i < 16384;  i += gs) z3[i] = 0u;
        for (int i = gt; i < 256;    i += gs) bar[i] = 0u;
    }
    grid.sync();   // CG barrier once: wbl2+inv publishes zeroed state to all XCDs.
                   // After this: h via sc0 (XCD-L2), stats/flags via sc1 (MALL).

    // pointwise for L1/L2 (8 ch per block): gates land as
    // lane n<8: acc0 = i-gate, acc1 = g-gate; lane n+8: acc0 = f, acc1 = o.
    auto pointwise12 = [&](float* cst, f16* hdst, float* redp, const float* bias,
                           f32x4 acc0, f32x4 acc1) {
        float fr[4], orr[4];
        #pragma unroll
        for (int r = 0; r < 4; ++r) {
            fr[r]  = __shfl_xor(acc0[r], 8);
            orr[r] = __shfl_xor(acc1[r], 8);
        }
        float s = 0.f, sq = 0.f;
        const int c = mlo & 7;
        if (mlo < 8) {
            const float bi = bias[c], bf = bias[8 + c], bg = bias[16 + c], bo = bias[24 + c];
            float4 cc = *(float4*)&cst[c * 132 + wv * 16 + q * 4];
            float cv[4] = {cc.x, cc.y, cc.z, cc.w};
            #pragma unroll
            for (int r = 0; r < 4; ++r) {
                const float gi = fsigmoid(acc0[r] + bi);
                const float gf = fsigmoid(fr[r] + bf);
                const float gg = ftanh(acc1[r] + bg);
                const float go = fsigmoid(orr[r] + bo);
                const float cn = gf * cv[r] + gi * gg;
                cv[r] = cn;
                const f16 h16 = (f16)(go * ftanh(cn));
                st_h2_sc0(&hdst[(size_t)(b0 + wv * 16 + q * 4 + r) * 256 + CG * 8 + c], h16);
                const float hq = (float)h16;
                s += hq; sq += hq * hq;
            }
            *(float4*)&cst[c * 132 + wv * 16 + q * 4] = make_float4(cv[0], cv[1], cv[2], cv[3]);
        }
        s  += __shfl_xor(s, 16);  s  += __shfl_xor(s, 32);
        sq += __shfl_xor(sq, 16); sq += __shfl_xor(sq, 32);
        if (mlo < 8 && q == 0) {
            redp[wv * 16 + c * 2]     = s;
            redp[wv * 16 + c * 2 + 1] = sq;
        }
    };

    // x-prefetch registers for L1 (loaded during previous barrier wait; x is immutable, cached)
    f16x8 xpre[4];
    auto loadx = [&](int t) {
        if (t < T) {
            const int brow = b0 + wv * 16 + mlo;
            #pragma unroll
            for (int kt = 0; kt < 4; ++kt) {
                const float* xp = x + ((size_t)brow * T + t) * 128 + kt * 32 + q * 8;
                const float4 u = *(const float4*)xp;
                const float4 v = *(const float4*)(xp + 4);
                f16x8 a;
                a[0] = (f16)u.x; a[1] = (f16)u.y; a[2] = (f16)u.z; a[3] = (f16)u.w;
                a[4] = (f16)v.x; a[5] = (f16)v.y; a[6] = (f16)v.z; a[7] = (f16)v.w;
                xpre[kt] = a;
            }
        }
    };
    loadx(0);

    // fold helper: z = a*h + d applied to one f16x8 with LDS tables at column k
    auto fold8 = [&](f16x8 a, const float* sA, const float* sD, int k) -> f16x8 {
        const float4 aa0 = *(const float4*)&sA[k];
        const float4 aa1 = *(const float4*)&sA[k + 4];
        const float4 dd0 = *(const float4*)&sD[k];
        const float4 dd1 = *(const float4*)&sD[k + 4];
        a[0] = (f16)(aa0.x * (float)a[0] + dd0.x);
        a[1] = (f16)(aa0.y * (float)a[1] + dd0.y);
        a[2] = (f16)(aa0.z * (float)a[2] + dd0.z);
        a[3] = (f16)(aa0.w * (float)a[3] + dd0.w);
        a[4] = (f16)(aa1.x * (float)a[4] + dd1.x);
        a[5] = (f16)(aa1.y * (float)a[5] + dd1.y);
        a[6] = (f16)(aa1.z * (float)a[6] + dd1.z);
        a[7] = (f16)(aa1.w * (float)a[7] + dd1.w);
        return a;
    };

    // ================= pipelined time loop =================
    // phase s computes: L1(s), L2(s-1), L3(s-2), head(s-3). ONE flat barrier per phase.
    // All cross-block loads of the phase issue in ONE window (ld_phase).
    for (int s = 0; s < T + 3; ++s) {
        const int t2 = s - 1, t3 = s - 2, th = s - 3;
        const int brow = b0 + wv * 16 + mlo;

        // ---------- mega-load: BN stats + h1(s-1) + h2(s-2) + h3(s-3) ----------
        // stat base: tid<256 -> BN1 slice (slot (s-1)&1), tid>=256 -> BN2 (slot (s-2)&1)
        const float* sp = stats + (tid < 256
                ? ((size_t)((s & 1) ^ 1) * 8704 + (size_t)tid * 16)
                : ((size_t)(s & 1) * 8704 + 4096 + (size_t)(tid - 256) * 16));
        const f16* p1 = h1x + (size_t)(s & 1) * B * 256 + (size_t)brow * 256 + q * 8;
        const f16* p2 = h2x + (size_t)((s & 1) ^ 1) * B * 256 + (size_t)brow * 256 + q * 8;
        const f16* p3 = h3x + (size_t)(s & 1) * B * 32 + (size_t)brow * 32 + q * 8;
        f32x4 r0, r1, r2, r3;
        f16x8 hd[8], he[8], hf;
        ld_phase(sp, p1, p2, p3, r0, r1, r2, r3,
                 hd[0], hd[1], hd[2], hd[3], hd[4], hd[5], hd[6], hd[7],
                 he[0], he[1], he[2], he[3], he[4], he[5], he[6], he[7], hf);

        // ---------- BN folds (from registers; loads already complete) ----------
        if (t2 >= 0 && t2 < T && tid < 256) {            // BN1(t2) for L2
            const float sv = r0[0] + r0[2] + r1[0] + r1[2] + r2[0] + r2[2] + r3[0] + r3[2];
            const float qv = r0[1] + r0[3] + r1[1] + r1[3] + r2[1] + r2[3] + r3[1] + r3[3];
            const float mu = sv * (1.f / B);
            const float var = qv * (1.f / B) - mu * mu;
            const float a = sG1[tid] * rsqrtf(var + EPS);
            sA1[tid] = a; sD1[tid] = sT1[tid] - mu * a;
        }
        if (t3 >= 0 && t3 < T && tid >= 256) {           // BN2(t3) for L3
            const int ch = tid - 256;
            const float sv = r0[0] + r0[2] + r1[0] + r1[2] + r2[0] + r2[2] + r3[0] + r3[2];
            const float qv = r0[1] + r0[3] + r1[1] + r1[3] + r2[1] + r2[3] + r3[1] + r3[3];
            const float mu = sv * (1.f / B);
            const float var = qv * (1.f / B) - mu * mu;
            const float a = sG2[ch] * rsqrtf(var + EPS);
            sA2[ch] = a; sD2[ch] = sT2[ch] - mu * a;
        }
        if (CG == 0 && th >= 0 && tid < 32) {            // BN3(th) for head
            const float* sp3 = stats + (size_t)(th & 1) * 8704 + 8192 + (size_t)tid * 16;
            float sv = 0.f, qv = 0.f;
            #pragma unroll
            for (int g = 0; g < 8; ++g) {
                sv += coh_ldf(sp3 + g * 2);
                qv += coh_ldf(sp3 + g * 2 + 1);
            }
            const float mu = sv * (1.f / B);
            const float var = qv * (1.f / B) - mu * mu;
            const float a = sG3[tid] * rsqrtf(var + EPS);
            sA3[tid] = a; sD3[tid] = sT3[tid] - mu * a;
        }

        // ---------- L1(s) : does not need BN folds -> before the syncthreads ----------
        if (s < T) {
            f16* h1c = h1x + (size_t)((s & 1) ^ 1) * B * 256;   // h1(s)
            f32x4 acc0 = {0.f, 0.f, 0.f, 0.f}, acc1 = {0.f, 0.f, 0.f, 0.f};
            #pragma unroll
            for (int kt = 0; kt < 12; ++kt) {
                const f16x8 av = (kt < 4) ? xpre[kt] : hd[kt - 4];
                const f16x8 bf0 = *(const f16x8*)(w1 + mlo * 392 + kt * 32 + q * 8);
                const f16x8 bf1 = *(const f16x8*)(w1 + (16 + mlo) * 392 + kt * 32 + q * 8);
                acc0 = __builtin_amdgcn_mfma_f32_16x16x32_f16(av, bf0, acc0, 0, 0, 0);
                acc1 = __builtin_amdgcn_mfma_f32_16x16x32_f16(av, bf1, acc1, 0, 0, 0);
            }
            pointwise12(c1, h1c, sR1, sB1, acc0, acc1);
        }
        __syncthreads();   // sA1/sD1, sA2/sD2 ready

        // ---------- L2(t2) : BN1 folded into h1 regs (same data L1 used) ----------
        if (t2 >= 0 && t2 < T) {
            f16* h2c = h2x + (size_t)(s & 1) * B * 256;          // h2(t2)
            f32x4 acc0 = {0.f, 0.f, 0.f, 0.f}, acc1 = {0.f, 0.f, 0.f, 0.f};
            #pragma unroll
            for (int kt = 0; kt < 16; ++kt) {
                const f16x8 av = (kt < 8) ? fold8(hd[kt], sA1, sD1, kt * 32 + q * 8)
                                          : he[kt - 8];
                const f16x8 bf0 = *(const f16x8*)(w2 + mlo * 520 + kt * 32 + q * 8);
                const f16x8 bf1 = *(const f16x8*)(w2 + (16 + mlo) * 520 + kt * 32 + q * 8);
                acc0 = __builtin_amdgcn_mfma_f32_16x16x32_f16(av, bf0, acc0, 0, 0, 0);
                acc1 = __builtin_amdgcn_mfma_f32_16x16x32_f16(av, bf1, acc1, 0, 0, 0);
            }
            pointwise12(c2, h2c, sR2, sB2, acc0, acc1);
        }

        // ---------- L3(t3) : BN2 folded into h2 regs (same data L2 used) ----------
        if (t3 >= 0 && t3 < T) {
            f16* h3c = h3x + (size_t)((s & 1) ^ 1) * B * 32;     // h3(t3)
            f32x4 acc0 = {0.f, 0.f, 0.f, 0.f};
            #pragma unroll
            for (int kt = 0; kt < 9; ++kt) {
                const f16x8 av = (kt < 8) ? fold8(he[kt], sA2, sD2, kt * 32 + q * 8) : hf;
                const f16x8 bf0 = *(const f16x8*)(w3 + mlo * 296 + kt * 32 + q * 8);
                acc0 = __builtin_amdgcn_mfma_f32_16x16x32_f16(av, bf0, acc0, 0, 0, 0);
            }
            float gi[4], gf_[4], gg_[4], go_[4];
            #pragma unroll
            for (int r = 0; r < 4; ++r) {
                gi[r]  = __shfl(acc0[r], (lane & 48) + 0);
                gf_[r] = __shfl(acc0[r], (lane & 48) + 1);
                gg_[r] = __shfl(acc0[r], (lane & 48) + 2);
                go_[r] = __shfl(acc0[r], (lane & 48) + 3);
            }
            float s_ = 0.f, sq = 0.f;
            if (mlo == 0) {
                float4 cc = *(float4*)&c3[wv * 16 + q * 4];
                float cv[4] = {cc.x, cc.y, cc.z, cc.w};
                #pragma unroll
                for (int r = 0; r < 4; ++r) {
                    const float i_ = fsigmoid(gi[r] + sB3[0]);
                    const float f_ = fsigmoid(gf_[r] + sB3[1]);
                    const float g_ = ftanh(gg_[r] + sB3[2]);
                    const float o_ = fsigmoid(go_[r] + sB3[3]);
                    const float cn = f_ * cv[r] + i_ * g_;
                    cv[r] = cn;
                    const f16 h16 = (f16)(o_ * ftanh(cn));
                    st_h2_sc0(&h3c[(size_t)(b0 + wv * 16 + q * 4 + r) * 32 + CG], h16);
                    const float hq = (float)h16;
                    s_ += hq; sq += hq * hq;
                }
                *(float4*)&c3[wv * 16 + q * 4] = make_float4(cv[0], cv[1], cv[2], cv[3]);
            }
            s_ += __shfl_xor(s_, 16); s_ += __shfl_xor(s_, 32);
            sq += __shfl_xor(sq, 16); sq += __shfl_xor(sq, 32);
            if (lane == 0) { sR3[wv * 2] = s_; sR3[wv * 2 + 1] = sq; }
        }

        // ---------- head(th) ----------
        if (CG == 0 && th >= 0) {
            const f16* hp3 = h3x + (size_t)(s & 1) * B * 32;   // h3(th)
            if (lane < 16) {
                const int b = b0 + wv * 16 + lane;
                const f16* hp = hp3 + (size_t)b * 32;
                f16x8 hv0, hv1, hv2, hv3;
                ld_h4_sc0(hp, hv0, hv1, hv2, hv3);
                float zz[32];
                #pragma unroll
                for (int k2 = 0; k2 < 8; ++k2) {
                    zz[k2]      = (float)hv0[k2];
                    zz[8 + k2]  = (float)hv1[k2];
                    zz[16 + k2] = (float)hv2[k2];
                    zz[24 + k2] = (float)hv3[k2];
                }
                float y0 = sHW[68], y1 = sHW[69];
                #pragma unroll
                for (int ch = 0; ch < 32; ++ch) {
                    const float z = sA3[ch] * zz[ch] + sD3[ch];
                    y0 += sHW[ch] * z; y1 += sHW[32 + ch] * z;
                }
                y0 = fmaxf(y0, 0.f); y1 = fmaxf(y1, 0.f);
                const float u0 = sHW[64] * y0 + sHW[65] * y1 + sHW[70];
                const float u1 = sHW[66] * y0 + sHW[67] * y1 + sHW[71];
                const float m = fmaxf(u0, u1);
                const float e0 = __expf(u0 - m), e1 = __expf(u1 - m);
                const float inv = 1.f / (e0 + e1);
                *(float2*)&out[((size_t)b * T + th) * 2] = make_float2(e0 * inv, e1 * inv);
            }
        }

        // ---------- stat reduce + flat flag barrier (R7-proven) ----------
        if (s < T + 2) {
            __syncthreads();   // all waves' h stores (L2) + LDS partials drained
            // cross-wave reduction -> channel-major stores [ch][BGr][2] (no atomics)
            if (s < T && tid < 16) {
                const int i = tid, ch = CG * 8 + (i >> 1), j = i & 1;
                float v = sR1[i];
                #pragma unroll
                for (int w = 1; w < 8; ++w) v += sR1[w * 16 + i];
                coh_stf(stats + (size_t)(s & 1) * 8704 + (size_t)ch * 16 + BGr * 2 + j, v);
            }
            if (t2 >= 0 && t2 < T && tid >= 16 && tid < 32) {
                const int i = tid - 16, ch = CG * 8 + (i >> 1), j = i & 1;
                float v = sR2[i];
                #pragma unroll
                for (int w = 1; w < 8; ++w) v += sR2[w * 16 + i];
                coh_stf(stats + (size_t)(t2 & 1) * 8704 + 4096 + (size_t)ch * 16 + BGr * 2 + j, v);
            }
            if (t3 >= 0 && t3 < T && tid >= 32 && tid < 34) {
                const int i = tid - 32;
                float v = sR3[i];
                #pragma unroll
                for (int w = 1; w < 8; ++w) v += sR3[w * 2 + i];
                coh_stf(stats + (size_t)(t3 & 1) * 8704 + 8192 + (size_t)CG * 16 + BGr * 2 + i, v);
            }
            __syncthreads();   // reducer sc1 stores drained (vmcnt(0) per wave before s_barrier)
            if (tid == 0)
                __hip_atomic_store(bar + blk, (unsigned)(s + 1),
                                   __ATOMIC_RELAXED, __HIP_MEMORY_SCOPE_AGENT);
            loadx(s + 1);                       // hide next x load+cvt under barrier wait
            if (wv == 0) {
                const unsigned tgt = (unsigned)(s + 1);
                u64* fl = (u64*)bar;            // 128 u64 covering 256 flags
                for (;;) {
                    const u64 a = __hip_atomic_load(fl + lane,
                                    __ATOMIC_RELAXED, __HIP_MEMORY_SCOPE_AGENT);
                    const u64 b = __hip_atomic_load(fl + 64 + lane,
                                    __ATOMIC_RELAXED, __HIP_MEMORY_SCOPE_AGENT);
                    const bool ok = ((unsigned)a >= tgt) && ((unsigned)(a >> 32) >= tgt) &&
                                    ((unsigned)b >= tgt) && ((unsigned)(b >> 32) >= tgt);
                    if (__all(ok)) break;
                    __builtin_amdgcn_s_sleep(1);
                }
            }
            __syncthreads();
        }
    }
}

extern "C" void kernel_launch(void* const* d_in, const int* in_sizes, int n_in,
                              void* d_out, int out_size, void* d_ws, size_t ws_size,
                              hipStream_t stream) {
    const float* x    = (const float*)d_in[0];
    const float* Wih1 = (const float*)d_in[1];
    const float* Whh1 = (const float*)d_in[2];
    const float* bih1 = (const float*)d_in[3];
    const float* bhh1 = (const float*)d_in[4];
    const float* g1   = (const float*)d_in[5];
    const float* b1   = (const float*)d_in[6];
    const float* Wih2 = (const float*)d_in[7];
    const float* Whh2 = (const float*)d_in[8];
    const float* bih2 = (const float*)d_in[9];
    const float* bhh2 = (const float*)d_in[10];
    const float* g2   = (const float*)d_in[11];
    const float* b2   = (const float*)d_in[12];
    const float* Wih3 = (const float*)d_in[13];
    const float* Whh3 = (const float*)d_in[14];
    const float* bih3 = (const float*)d_in[15];
    const float* bhh3 = (const float*)d_in[16];
    const float* g3   = (const float*)d_in[17];
    const float* b3   = (const float*)d_in[18];
    const float* Wl   = (const float*)d_in[19];
    const float* bl   = (const float*)d_in[20];
    const float* Wl2  = (const float*)d_in[21];
    const float* bl2  = (const float*)d_in[22];
    float* out = (float*)d_out;
    float* ws  = (float*)d_ws;

    const int dyn_lds = LDSBYTES;
    hipFuncSetAttribute((const void*)cryptonet_kernel,
                        hipFuncAttributeMaxDynamicSharedMemorySize, dyn_lds);

    void* args[] = { &x, &Wih1, &Whh1, &bih1, &bhh1, &g1, &b1,
                     &Wih2, &Whh2, &bih2, &bhh2, &g2, &b2,
                     &Wih3, &Whh3, &bih3, &bhh3, &g3, &b3,
                     &Wl, &bl, &Wl2, &bl2, &out, &ws };
    hipLaunchCooperativeKernel((const void*)cryptonet_kernel, dim3(NBLK), dim3(NTHR),
                               args, dyn_lds, stream);
}

// Round 11
// 4547.670 us; speedup vs baseline: 1.0960x; 1.0731x over previous
//
#include <hip/hip_runtime.h>
#include <hip/hip_cooperative_groups.h>

namespace cg = cooperative_groups;

#define B    1024
#define T    256
#define NBLK 256
#define NTHR 512
#define EPS  1e-5f

typedef _Float16 f16;
typedef _Float16 f16x8 __attribute__((ext_vector_type(8)));
typedef float    f32x4 __attribute__((ext_vector_type(4)));
typedef unsigned long long u64;

// ---- ws byte offsets ----
#define WS_H1X 0u            // f16 [2][1024][256]   h1(t) stored in buf[(t+1)&1]
#define WS_H2X 1048576u      // f16 [2][1024][256]
#define WS_H3X 2097152u      // f16 [2][1024][32]
#define WS_ST  2228224u      // f32 [2 slot][8704]: st1 [256ch][8g][2] | +4096 st2 | +8192 st3 [32ch][8g][2]
#define WS_BAR 2297856u      // uint flags[8 BGr][32 CG], monotonic epoch values (MALL)

// ---- dynamic LDS byte offsets ----
#define OW1 0        // f16[32][392]  W1 slice, rr = g*8+c, k-contig
#define OW2 25088    // f16[32][520]
#define OW3 58368    // f16[16][296]  (rows 4..15 zero pad)
#define OA1 67840    // f32[256] BN1 scale a
#define OD1 68864    // f32[256] BN1 shift d
#define OB1 69888    // f32[32]
#define OB2 70016    // f32[32]
#define OB3 70144    // f32[4]
#define OA3 70160    // f32[32]
#define OD3 70288    // f32[32]
#define OHW 70416    // f32[72]: Wl(64) Wl2(4) bl(2) bl2(2)
#define OC1 70704    // f32[8][132]
#define OC2 74928    // f32[8][132]
#define OC3 79152    // f32[132]
#define OA2 79680    // f32[256] BN2 scale a
#define OD2 80704    // f32[256] BN2 shift d
#define OG1 81728    // f32[256] gamma1
#define OT1 82752    // f32[256] beta1
#define OG2 83776    // f32[256] gamma2
#define OT2 84800    // f32[256] beta2
#define OG3 85824    // f32[32]  gamma3
#define OT3 85952    // f32[32]  beta3
#define OR1 86080    // f32[8][16] wave-partial stats L1
#define OR2 86592    // f32[8][16] wave-partial stats L2
#define OR3 87104    // f32[8][2]  wave-partial stats L3
#define LDSBYTES 87168

__device__ __forceinline__ float fsigmoid(float v) { return 1.f / (1.f + __expf(-v)); }
__device__ __forceinline__ float ftanh(float v)    { return 1.f - 2.f / (__expf(2.f * v) + 1.f); }

// ---- agent-coherent accessors (MALL) — cross-XCD stats & barrier flags ----
__device__ __forceinline__ float coh_ldf(const float* p) {
    return __hip_atomic_load(p, __ATOMIC_RELAXED, __HIP_MEMORY_SCOPE_AGENT);
}
__device__ __forceinline__ void coh_stf(float* p, float v) {
    __hip_atomic_store(p, v, __ATOMIC_RELAXED, __HIP_MEMORY_SCOPE_AGENT);
}

// ---- intra-XCD h1 load (sc0 = L1-bypass, XCD-L2): gates ONLY on own-group barrier ----
__device__ __forceinline__ void ld_h8_sc0(const f16* p, f16x8& d0, f16x8& d1, f16x8& d2,
                                          f16x8& d3, f16x8& d4, f16x8& d5, f16x8& d6, f16x8& d7) {
    asm volatile(
        "global_load_dwordx4 %0, %8, off sc0\n\t"
        "global_load_dwordx4 %1, %8, off offset:64 sc0\n\t"
        "global_load_dwordx4 %2, %8, off offset:128 sc0\n\t"
        "global_load_dwordx4 %3, %8, off offset:192 sc0\n\t"
        "global_load_dwordx4 %4, %8, off offset:256 sc0\n\t"
        "global_load_dwordx4 %5, %8, off offset:320 sc0\n\t"
        "global_load_dwordx4 %6, %8, off offset:384 sc0\n\t"
        "global_load_dwordx4 %7, %8, off offset:448 sc0\n\t"
        "s_waitcnt vmcnt(0)"
        : "=&v"(d0), "=&v"(d1), "=&v"(d2), "=&v"(d3),
          "=&v"(d4), "=&v"(d5), "=&v"(d6), "=&v"(d7)
        : "v"(p) : "memory");
}
// ---- post-global-poll window: BN stats (MALL) + h2 + h3 in one issue window ----
__device__ __forceinline__ void ld_sh13(const float* sp, const f16* p2, const f16* p3,
    f32x4& r0, f32x4& r1, f32x4& r2, f32x4& r3,
    f16x8& e0, f16x8& e1, f16x8& e2, f16x8& e3,
    f16x8& e4, f16x8& e5, f16x8& e6, f16x8& e7,
    f16x8& f0) {
    asm volatile(
        "global_load_dwordx4 %0, %13, off sc0 sc1\n\t"
        "global_load_dwordx4 %1, %13, off offset:16 sc0 sc1\n\t"
        "global_load_dwordx4 %2, %13, off offset:32 sc0 sc1\n\t"
        "global_load_dwordx4 %3, %13, off offset:48 sc0 sc1\n\t"
        "global_load_dwordx4 %4, %14, off sc0\n\t"
        "global_load_dwordx4 %5, %14, off offset:64 sc0\n\t"
        "global_load_dwordx4 %6, %14, off offset:128 sc0\n\t"
        "global_load_dwordx4 %7, %14, off offset:192 sc0\n\t"
        "global_load_dwordx4 %8, %14, off offset:256 sc0\n\t"
        "global_load_dwordx4 %9, %14, off offset:320 sc0\n\t"
        "global_load_dwordx4 %10, %14, off offset:384 sc0\n\t"
        "global_load_dwordx4 %11, %14, off offset:448 sc0\n\t"
        "global_load_dwordx4 %12, %15, off sc0\n\t"
        "s_waitcnt vmcnt(0)"
        : "=&v"(r0), "=&v"(r1), "=&v"(r2), "=&v"(r3),
          "=&v"(e0), "=&v"(e1), "=&v"(e2), "=&v"(e3),
          "=&v"(e4), "=&v"(e5), "=&v"(e6), "=&v"(e7),
          "=&v"(f0)
        : "v"(sp), "v"(p2), "v"(p3) : "memory");
}
__device__ __forceinline__ void ld_h4_sc0(const f16* p, f16x8& d0, f16x8& d1, f16x8& d2, f16x8& d3) {
    asm volatile(
        "global_load_dwordx4 %0, %4, off sc0\n\t"
        "global_load_dwordx4 %1, %4, off offset:16 sc0\n\t"
        "global_load_dwordx4 %2, %4, off offset:32 sc0\n\t"
        "global_load_dwordx4 %3, %4, off offset:48 sc0\n\t"
        "s_waitcnt vmcnt(0)"
        : "=&v"(d0), "=&v"(d1), "=&v"(d2), "=&v"(d3)
        : "v"(p) : "memory");
}
__device__ __forceinline__ void st_h2_sc0(f16* p, f16 v) {
    asm volatile("global_store_short %0, %1, off sc0" :: "v"(p), "v"(v) : "memory");
}

__global__ void __launch_bounds__(NTHR) cryptonet_kernel(
    const float* __restrict__ x,
    const float* __restrict__ Wih1, const float* __restrict__ Whh1,
    const float* __restrict__ bih1, const float* __restrict__ bhh1,
    const float* __restrict__ g1v,  const float* __restrict__ b1v,
    const float* __restrict__ Wih2, const float* __restrict__ Whh2,
    const float* __restrict__ bih2, const float* __restrict__ bhh2,
    const float* __restrict__ g2v,  const float* __restrict__ b2v,
    const float* __restrict__ Wih3, const float* __restrict__ Whh3,
    const float* __restrict__ bih3, const float* __restrict__ bhh3,
    const float* __restrict__ g3v,  const float* __restrict__ b3v,
    const float* __restrict__ Wl,   const float* __restrict__ bl,
    const float* __restrict__ Wl2,  const float* __restrict__ bl2,
    float* __restrict__ out, float* __restrict__ ws)
{
    cg::grid_group grid = cg::this_grid();
    const int tid  = threadIdx.x;
    const int blk  = blockIdx.x;
    const int CG   = blk >> 3;        // 0..31 channel group (8 ch of H1/H2, 1 ch of H3)
    const int BGr  = blk & 7;         // 0..7 batch group == XCD (R7-validated)
    const int b0   = BGr * 128;
    const int wv   = tid >> 6;        // wave = m-tile 0..7
    const int lane = tid & 63;
    const int q    = lane >> 4;       // quad
    const int mlo  = lane & 15;

    extern __shared__ char smraw[];
    f16*   w1  = (f16*)(smraw + OW1);
    f16*   w2  = (f16*)(smraw + OW2);
    f16*   w3  = (f16*)(smraw + OW3);
    float* sA1 = (float*)(smraw + OA1);
    float* sD1 = (float*)(smraw + OD1);
    float* sA2 = (float*)(smraw + OA2);
    float* sD2 = (float*)(smraw + OD2);
    float* sB1 = (float*)(smraw + OB1);
    float* sB2 = (float*)(smraw + OB2);
    float* sB3 = (float*)(smraw + OB3);
    float* sA3 = (float*)(smraw + OA3);
    float* sD3 = (float*)(smraw + OD3);
    float* sHW = (float*)(smraw + OHW);
    float* c1  = (float*)(smraw + OC1);
    float* c2  = (float*)(smraw + OC2);
    float* c3  = (float*)(smraw + OC3);
    float* sG1 = (float*)(smraw + OG1);
    float* sT1 = (float*)(smraw + OT1);
    float* sG2 = (float*)(smraw + OG2);
    float* sT2 = (float*)(smraw + OT2);
    float* sG3 = (float*)(smraw + OG3);
    float* sT3 = (float*)(smraw + OT3);
    float* sR1 = (float*)(smraw + OR1);   // [8][16] wave partials st1
    float* sR2 = (float*)(smraw + OR2);   // [8][16] wave partials st2
    float* sR3 = (float*)(smraw + OR3);   // [8][2]  wave partials st3

    char* ws8 = (char*)ws;
    f16*   h1x   = (f16*)(ws8 + WS_H1X);
    f16*   h2x   = (f16*)(ws8 + WS_H2X);
    f16*   h3x   = (f16*)(ws8 + WS_H3X);
    float* stats = (float*)(ws8 + WS_ST);   // [2][8704] channel-major [ch][BGr][2]
    unsigned* bar = (unsigned*)(ws8 + WS_BAR);   // [8 BGr][32 CG]

    // ================= init: weights -> LDS (fp16), biases, zero state =================
    for (int idx = tid; idx < 32 * 384; idx += NTHR) {
        const int rr = idx / 384, k = idx - rr * 384;
        const int j = (rr >> 3) * 256 + CG * 8 + (rr & 7);
        const float v = (k < 128) ? Wih1[(size_t)j * 128 + k] : Whh1[(size_t)j * 256 + (k - 128)];
        w1[rr * 392 + k] = (f16)v;
    }
    for (int idx = tid; idx < 32 * 512; idx += NTHR) {
        const int rr = idx >> 9, k = idx & 511;
        const int j = (rr >> 3) * 256 + CG * 8 + (rr & 7);
        const float v = (k < 256) ? Wih2[(size_t)j * 256 + k] : Whh2[(size_t)j * 256 + (k - 256)];
        w2[rr * 520 + k] = (f16)v;
    }
    for (int idx = tid; idx < 16 * 296; idx += NTHR) w3[idx] = (f16)0.f;
    __syncthreads();
    for (int idx = tid; idx < 4 * 288; idx += NTHR) {
        const int rr = idx / 288, k = idx - rr * 288;  // rr = gate g
        const int j = rr * 32 + CG;
        const float v = (k < 256) ? Wih3[(size_t)j * 256 + k] : Whh3[(size_t)j * 32 + (k - 256)];
        w3[rr * 296 + k] = (f16)v;
    }
    if (tid < 32) {
        const int j = (tid >> 3) * 256 + CG * 8 + (tid & 7);
        sB1[tid] = bih1[j] + bhh1[j];
        sB2[tid] = bih2[j] + bhh2[j];
    }
    if (tid >= 32 && tid < 36) {
        const int g = tid - 32;
        sB3[g] = bih3[g * 32 + CG] + bhh3[g * 32 + CG];
    }
    if (tid >= 64 && tid < 136) {
        const int i = tid - 64;
        float v;
        if (i < 64) v = Wl[i];
        else if (i < 68) v = Wl2[i - 64];
        else if (i < 70) v = bl[i - 68];
        else v = bl2[i - 70];
        sHW[i] = v;
    }
    if (tid < 256) {                   // BN param tables -> LDS
        sG1[tid] = g1v[tid]; sT1[tid] = b1v[tid];
        sG2[tid] = g2v[tid]; sT2[tid] = b2v[tid];
        if (tid < 32) { sG3[tid] = g3v[tid]; sT3[tid] = b3v[tid]; }
    }
    for (int i = tid; i < 8 * 132; i += NTHR) { c1[i] = 0.f; c2[i] = 0.f; }
    if (tid < 132) c3[tid] = 0.f;
    // zero global: H1X[0], H2X[0], H3X[0], barrier flags (ws poisoned each call).
    {
        unsigned int* z1 = (unsigned int*)h1x;
        unsigned int* z2 = (unsigned int*)h2x;
        unsigned int* z3 = (unsigned int*)h3x;
        const int gt = blk * NTHR + tid, gs = NBLK * NTHR;
        for (int i = gt; i < 131072; i += gs) z1[i] = 0u;   // buf 0 (t=-1)
        for (int i = gt; i < 131072; i += gs) z2[i] = 0u;
        for (int i = gt; i < 16384;  i += gs) z3[i] = 0u;
        for (int i = gt; i < 256;    i += gs) bar[i] = 0u;
    }
    grid.sync();   // CG barrier once: wbl2+inv publishes zeroed state to all XCDs.
                   // After this: h via sc0 (XCD-L2), stats/flags via sc1 (MALL).

    // pointwise for L1/L2 (8 ch per block): gates land as
    // lane n<8: acc0 = i-gate, acc1 = g-gate; lane n+8: acc0 = f, acc1 = o.
    auto pointwise12 = [&](float* cst, f16* hdst, float* redp, const float* bias,
                           f32x4 acc0, f32x4 acc1) {
        float fr[4], orr[4];
        #pragma unroll
        for (int r = 0; r < 4; ++r) {
            fr[r]  = __shfl_xor(acc0[r], 8);
            orr[r] = __shfl_xor(acc1[r], 8);
        }
        float s = 0.f, sq = 0.f;
        const int c = mlo & 7;
        if (mlo < 8) {
            const float bi = bias[c], bf = bias[8 + c], bg = bias[16 + c], bo = bias[24 + c];
            float4 cc = *(float4*)&cst[c * 132 + wv * 16 + q * 4];
            float cv[4] = {cc.x, cc.y, cc.z, cc.w};
            #pragma unroll
            for (int r = 0; r < 4; ++r) {
                const float gi = fsigmoid(acc0[r] + bi);
                const float gf = fsigmoid(fr[r] + bf);
                const float gg = ftanh(acc1[r] + bg);
                const float go = fsigmoid(orr[r] + bo);
                const float cn = gf * cv[r] + gi * gg;
                cv[r] = cn;
                const f16 h16 = (f16)(go * ftanh(cn));
                st_h2_sc0(&hdst[(size_t)(b0 + wv * 16 + q * 4 + r) * 256 + CG * 8 + c], h16);
                const float hq = (float)h16;
                s += hq; sq += hq * hq;
            }
            *(float4*)&cst[c * 132 + wv * 16 + q * 4] = make_float4(cv[0], cv[1], cv[2], cv[3]);
        }
        s  += __shfl_xor(s, 16);  s  += __shfl_xor(s, 32);
        sq += __shfl_xor(sq, 16); sq += __shfl_xor(sq, 32);
        if (mlo < 8 && q == 0) {
            redp[wv * 16 + c * 2]     = s;
            redp[wv * 16 + c * 2 + 1] = sq;
        }
    };

    // x-prefetch registers for L1 (loaded during previous barrier wait; x is immutable, cached)
    f16x8 xpre[4];
    auto loadx = [&](int t) {
        if (t < T) {
            const int brow = b0 + wv * 16 + mlo;
            #pragma unroll
            for (int kt = 0; kt < 4; ++kt) {
                const float* xp = x + ((size_t)brow * T + t) * 128 + kt * 32 + q * 8;
                const float4 u = *(const float4*)xp;
                const float4 v = *(const float4*)(xp + 4);
                f16x8 a;
                a[0] = (f16)u.x; a[1] = (f16)u.y; a[2] = (f16)u.z; a[3] = (f16)u.w;
                a[4] = (f16)v.x; a[5] = (f16)v.y; a[6] = (f16)v.z; a[7] = (f16)v.w;
                xpre[kt] = a;
            }
        }
    };
    loadx(0);

    // fold helper: z = a*h + d applied to one f16x8 with LDS tables at column k
    auto fold8 = [&](f16x8 a, const float* sA, const float* sD, int k) -> f16x8 {
        const float4 aa0 = *(const float4*)&sA[k];
        const float4 aa1 = *(const float4*)&sA[k + 4];
        const float4 dd0 = *(const float4*)&sD[k];
        const float4 dd1 = *(const float4*)&sD[k + 4];
        a[0] = (f16)(aa0.x * (float)a[0] + dd0.x);
        a[1] = (f16)(aa0.y * (float)a[1] + dd0.y);
        a[2] = (f16)(aa0.z * (float)a[2] + dd0.z);
        a[3] = (f16)(aa0.w * (float)a[3] + dd0.w);
        a[4] = (f16)(aa1.x * (float)a[4] + dd1.x);
        a[5] = (f16)(aa1.y * (float)a[5] + dd1.y);
        a[6] = (f16)(aa1.z * (float)a[6] + dd1.z);
        a[7] = (f16)(aa1.w * (float)a[7] + dd1.w);
        return a;
    };

    // ================= pipelined time loop =================
    // phase s: L1(s) gated on OWN-XCD barrier only (h1 is intra-XCD); global (cross-XCD)
    // rendezvous verified AFTER L1 — its MALL RTT + skew hide under L1's compute.
    for (int s = 0; s < T + 3; ++s) {
        const int t2 = s - 1, t3 = s - 2, th = s - 3;
        const int brow = b0 + wv * 16 + mlo;

        // ---------- L1(s): h1(s-1) is same-XCD data (own-group barrier verified) ----------
        f16x8 hd[8];
        ld_h8_sc0(h1x + (size_t)(s & 1) * B * 256 + (size_t)brow * 256 + q * 8,
                  hd[0], hd[1], hd[2], hd[3], hd[4], hd[5], hd[6], hd[7]);
        if (s < T) {
            f16* h1c = h1x + (size_t)((s & 1) ^ 1) * B * 256;   // h1(s)
            f32x4 acc0 = {0.f, 0.f, 0.f, 0.f}, acc1 = {0.f, 0.f, 0.f, 0.f};
            #pragma unroll
            for (int kt = 0; kt < 12; ++kt) {
                const f16x8 av = (kt < 4) ? xpre[kt] : hd[kt - 4];
                const f16x8 bf0 = *(const f16x8*)(w1 + mlo * 392 + kt * 32 + q * 8);
                const f16x8 bf1 = *(const f16x8*)(w1 + (16 + mlo) * 392 + kt * 32 + q * 8);
                acc0 = __builtin_amdgcn_mfma_f32_16x16x32_f16(av, bf0, acc0, 0, 0, 0);
                acc1 = __builtin_amdgcn_mfma_f32_16x16x32_f16(av, bf1, acc1, 0, 0, 0);
            }
            pointwise12(c1, h1c, sR1, sB1, acc0, acc1);
        }

        // ---------- global rendezvous (all 256 finished s-1), AFTER L1 ----------
        if (wv == 0 && s > 0) {
            const unsigned tgt = (unsigned)s;
            u64* fl = (u64*)bar;
            for (;;) {
                const u64 a = __hip_atomic_load(fl + lane,
                                __ATOMIC_RELAXED, __HIP_MEMORY_SCOPE_AGENT);
                const u64 b = __hip_atomic_load(fl + 64 + lane,
                                __ATOMIC_RELAXED, __HIP_MEMORY_SCOPE_AGENT);
                const bool ok = ((unsigned)a >= tgt) && ((unsigned)(a >> 32) >= tgt) &&
                                ((unsigned)b >= tgt) && ((unsigned)(b >> 32) >= tgt);
                if (__all(ok)) break;
                __builtin_amdgcn_s_sleep(1);
            }
        }
        __syncthreads();   // global condition holds for all waves; L1 done (sR1 written)

        // ---------- stats (MALL) + h2(s-2) + h3(s-2..3) in one window ----------
        const float* sp = stats + (tid < 256
                ? ((size_t)((s & 1) ^ 1) * 8704 + (size_t)tid * 16)
                : ((size_t)(s & 1) * 8704 + 4096 + (size_t)(tid - 256) * 16));
        const f16* p2 = h2x + (size_t)((s & 1) ^ 1) * B * 256 + (size_t)brow * 256 + q * 8;
        const f16* p3 = h3x + (size_t)(s & 1) * B * 32 + (size_t)brow * 32 + q * 8;
        f32x4 r0, r1, r2, r3;
        f16x8 he[8], hf;
        ld_sh13(sp, p2, p3, r0, r1, r2, r3,
                he[0], he[1], he[2], he[3], he[4], he[5], he[6], he[7], hf);

        // ---------- BN folds (from registers) ----------
        if (t2 >= 0 && t2 < T && tid < 256) {            // BN1(t2) for L2
            const float sv = r0[0] + r0[2] + r1[0] + r1[2] + r2[0] + r2[2] + r3[0] + r3[2];
            const float qv = r0[1] + r0[3] + r1[1] + r1[3] + r2[1] + r2[3] + r3[1] + r3[3];
            const float mu = sv * (1.f / B);
            const float var = qv * (1.f / B) - mu * mu;
            const float a = sG1[tid] * rsqrtf(var + EPS);
            sA1[tid] = a; sD1[tid] = sT1[tid] - mu * a;
        }
        if (t3 >= 0 && t3 < T && tid >= 256) {           // BN2(t3) for L3
            const int ch = tid - 256;
            const float sv = r0[0] + r0[2] + r1[0] + r1[2] + r2[0] + r2[2] + r3[0] + r3[2];
            const float qv = r0[1] + r0[3] + r1[1] + r1[3] + r2[1] + r2[3] + r3[1] + r3[3];
            const float mu = sv * (1.f / B);
            const float var = qv * (1.f / B) - mu * mu;
            const float a = sG2[ch] * rsqrtf(var + EPS);
            sA2[ch] = a; sD2[ch] = sT2[ch] - mu * a;
        }
        if (CG == 0 && th >= 0 && tid < 32) {            // BN3(th) for head
            const float* sp3 = stats + (size_t)(th & 1) * 8704 + 8192 + (size_t)tid * 16;
            float sv = 0.f, qv = 0.f;
            #pragma unroll
            for (int g = 0; g < 8; ++g) {
                sv += coh_ldf(sp3 + g * 2);
                qv += coh_ldf(sp3 + g * 2 + 1);
            }
            const float mu = sv * (1.f / B);
            const float var = qv * (1.f / B) - mu * mu;
            const float a = sG3[tid] * rsqrtf(var + EPS);
            sA3[tid] = a; sD3[tid] = sT3[tid] - mu * a;
        }
        __syncthreads();   // sA1/sD1, sA2/sD2, sA3/sD3 ready

        // ---------- L2(t2) : BN1 folded into h1 regs (same data L1 used) ----------
        if (t2 >= 0 && t2 < T) {
            f16* h2c = h2x + (size_t)(s & 1) * B * 256;          // h2(t2)
            f32x4 acc0 = {0.f, 0.f, 0.f, 0.f}, acc1 = {0.f, 0.f, 0.f, 0.f};
            #pragma unroll
            for (int kt = 0; kt < 16; ++kt) {
                const f16x8 av = (kt < 8) ? fold8(hd[kt], sA1, sD1, kt * 32 + q * 8)
                                          : he[kt - 8];
                const f16x8 bf0 = *(const f16x8*)(w2 + mlo * 520 + kt * 32 + q * 8);
                const f16x8 bf1 = *(const f16x8*)(w2 + (16 + mlo) * 520 + kt * 32 + q * 8);
                acc0 = __builtin_amdgcn_mfma_f32_16x16x32_f16(av, bf0, acc0, 0, 0, 0);
                acc1 = __builtin_amdgcn_mfma_f32_16x16x32_f16(av, bf1, acc1, 0, 0, 0);
            }
            pointwise12(c2, h2c, sR2, sB2, acc0, acc1);
        }

        // ---------- L3(t3) : BN2 folded into h2 regs (same data L2 used) ----------
        if (t3 >= 0 && t3 < T) {
            f16* h3c = h3x + (size_t)((s & 1) ^ 1) * B * 32;     // h3(t3)
            f32x4 acc0 = {0.f, 0.f, 0.f, 0.f};
            #pragma unroll
            for (int kt = 0; kt < 9; ++kt) {
                const f16x8 av = (kt < 8) ? fold8(he[kt], sA2, sD2, kt * 32 + q * 8) : hf;
                const f16x8 bf0 = *(const f16x8*)(w3 + mlo * 296 + kt * 32 + q * 8);
                acc0 = __builtin_amdgcn_mfma_f32_16x16x32_f16(av, bf0, acc0, 0, 0, 0);
            }
            float gi[4], gf_[4], gg_[4], go_[4];
            #pragma unroll
            for (int r = 0; r < 4; ++r) {
                gi[r]  = __shfl(acc0[r], (lane & 48) + 0);
                gf_[r] = __shfl(acc0[r], (lane & 48) + 1);
                gg_[r] = __shfl(acc0[r], (lane & 48) + 2);
                go_[r] = __shfl(acc0[r], (lane & 48) + 3);
            }
            float s_ = 0.f, sq = 0.f;
            if (mlo == 0) {
                float4 cc = *(float4*)&c3[wv * 16 + q * 4];
                float cv[4] = {cc.x, cc.y, cc.z, cc.w};
                #pragma unroll
                for (int r = 0; r < 4; ++r) {
                    const float i_ = fsigmoid(gi[r] + sB3[0]);
                    const float f_ = fsigmoid(gf_[r] + sB3[1]);
                    const float g_ = ftanh(gg_[r] + sB3[2]);
                    const float o_ = fsigmoid(go_[r] + sB3[3]);
                    const float cn = f_ * cv[r] + i_ * g_;
                    cv[r] = cn;
                    const f16 h16 = (f16)(o_ * ftanh(cn));
                    st_h2_sc0(&h3c[(size_t)(b0 + wv * 16 + q * 4 + r) * 32 + CG], h16);
                    const float hq = (float)h16;
                    s_ += hq; sq += hq * hq;
                }
                *(float4*)&c3[wv * 16 + q * 4] = make_float4(cv[0], cv[1], cv[2], cv[3]);
            }
            s_ += __shfl_xor(s_, 16); s_ += __shfl_xor(s_, 32);
            sq += __shfl_xor(sq, 16); sq += __shfl_xor(sq, 32);
            if (lane == 0) { sR3[wv * 2] = s_; sR3[wv * 2 + 1] = sq; }
        }

        // ---------- head(th) ----------
        if (CG == 0 && th >= 0) {
            const f16* hp3 = h3x + (size_t)(s & 1) * B * 32;   // h3(th)
            if (lane < 16) {
                const int b = b0 + wv * 16 + lane;
                const f16* hp = hp3 + (size_t)b * 32;
                f16x8 hv0, hv1, hv2, hv3;
                ld_h4_sc0(hp, hv0, hv1, hv2, hv3);
                float zz[32];
                #pragma unroll
                for (int k2 = 0; k2 < 8; ++k2) {
                    zz[k2]      = (float)hv0[k2];
                    zz[8 + k2]  = (float)hv1[k2];
                    zz[16 + k2] = (float)hv2[k2];
                    zz[24 + k2] = (float)hv3[k2];
                }
                float y0 = sHW[68], y1 = sHW[69];
                #pragma unroll
                for (int ch = 0; ch < 32; ++ch) {
                    const float z = sA3[ch] * zz[ch] + sD3[ch];
                    y0 += sHW[ch] * z; y1 += sHW[32 + ch] * z;
                }
                y0 = fmaxf(y0, 0.f); y1 = fmaxf(y1, 0.f);
                const float u0 = sHW[64] * y0 + sHW[65] * y1 + sHW[70];
                const float u1 = sHW[66] * y0 + sHW[67] * y1 + sHW[71];
                const float m = fmaxf(u0, u1);
                const float e0 = __expf(u0 - m), e1 = __expf(u1 - m);
                const float inv = 1.f / (e0 + e1);
                *(float2*)&out[((size_t)b * T + th) * 2] = make_float2(e0 * inv, e1 * inv);
            }
        }

        // ---------- stat reduce + flag + OWN-XCD barrier (strict, 2 MALL lines) ----------
        if (s < T + 2) {
            __syncthreads();   // all waves' h stores (L2) + LDS partials drained
            // cross-wave reduction -> channel-major stores [ch][BGr][2] (no atomics)
            if (s < T && tid < 16) {
                const int i = tid, ch = CG * 8 + (i >> 1), j = i & 1;
                float v = sR1[i];
                #pragma unroll
                for (int w = 1; w < 8; ++w) v += sR1[w * 16 + i];
                coh_stf(stats + (size_t)(s & 1) * 8704 + (size_t)ch * 16 + BGr * 2 + j, v);
            }
            if (t2 >= 0 && t2 < T && tid >= 16 && tid < 32) {
                const int i = tid - 16, ch = CG * 8 + (i >> 1), j = i & 1;
                float v = sR2[i];
                #pragma unroll
                for (int w = 1; w < 8; ++w) v += sR2[w * 16 + i];
                coh_stf(stats + (size_t)(t2 & 1) * 8704 + 4096 + (size_t)ch * 16 + BGr * 2 + j, v);
            }
            if (t3 >= 0 && t3 < T && tid >= 32 && tid < 34) {
                const int i = tid - 32;
                float v = sR3[i];
                #pragma unroll
                for (int w = 1; w < 8; ++w) v += sR3[w * 2 + i];
                coh_stf(stats + (size_t)(t3 & 1) * 8704 + 8192 + (size_t)CG * 16 + BGr * 2 + i, v);
            }
            __syncthreads();   // reducer sc1 stores drained (vmcnt(0) per wave before s_barrier)
            if (tid == 0)
                __hip_atomic_store(bar + BGr * 32 + CG, (unsigned)(s + 1),
                                   __ATOMIC_RELAXED, __HIP_MEMORY_SCOPE_AGENT);
            loadx(s + 1);      // hide next x load+cvt under barrier wait
            if (wv == 0) {     // strict own-XCD barrier: 16 u64 = 2 MALL lines
                const unsigned tgt = (unsigned)(s + 1);
                u64* fl = (u64*)bar + BGr * 16;
                for (;;) {
                    const u64 a = (lane < 16)
                        ? __hip_atomic_load(fl + lane, __ATOMIC_RELAXED, __HIP_MEMORY_SCOPE_AGENT)
                        : ~0ull;
                    const bool ok = ((unsigned)a >= tgt) && ((unsigned)(a >> 32) >= tgt);
                    if (__all(ok)) break;
                    __builtin_amdgcn_s_sleep(1);
                }
            }
            __syncthreads();
        }
    }
}

extern "C" void kernel_launch(void* const* d_in, const int* in_sizes, int n_in,
                              void* d_out, int out_size, void* d_ws, size_t ws_size,
                              hipStream_t stream) {
    const float* x    = (const float*)d_in[0];
    const float* Wih1 = (const float*)d_in[1];
    const float* Whh1 = (const float*)d_in[2];
    const float* bih1 = (const float*)d_in[3];
    const float* bhh1 = (const float*)d_in[4];
    const float* g1   = (const float*)d_in[5];
    const float* b1   = (const float*)d_in[6];
    const float* Wih2 = (const float*)d_in[7];
    const float* Whh2 = (const float*)d_in[8];
    const float* bih2 = (const float*)d_in[9];
    const float* bhh2 = (const float*)d_in[10];
    const float* g2   = (const float*)d_in[11];
    const float* b2   = (const float*)d_in[12];
    const float* Wih3 = (const float*)d_in[13];
    const float* Whh3 = (const float*)d_in[14];
    const float* bih3 = (const float*)d_in[15];
    const float* bhh3 = (const float*)d_in[16];
    const float* g3   = (const float*)d_in[17];
    const float* b3   = (const float*)d_in[18];
    const float* Wl   = (const float*)d_in[19];
    const float* bl   = (const float*)d_in[20];
    const float* Wl2  = (const float*)d_in[21];
    const float* bl2  = (const float*)d_in[22];
    float* out = (float*)d_out;
    float* ws  = (float*)d_ws;

    const int dyn_lds = LDSBYTES;
    hipFuncSetAttribute((const void*)cryptonet_kernel,
                        hipFuncAttributeMaxDynamicSharedMemorySize, dyn_lds);

    void* args[] = { &x, &Wih1, &Whh1, &bih1, &bhh1, &g1, &b1,
                     &Wih2, &Whh2, &bih2, &bhh2, &g2, &b2,
                     &Wih3, &Whh3, &bih3, &bhh3, &g3, &b3,
                     &Wl, &bl, &Wl2, &bl2, &out, &ws };
    hipLaunchCooperativeKernel((const void*)cryptonet_kernel, dim3(NBLK), dim3(NTHR),
                               args, dyn_lds, stream);
}